// Round 11
// baseline (641.110 us; speedup 1.0000x reference)
//
#include <hip/hip_runtime.h>
#include <stdint.h>

#define NN 50000
#define NE 800000
#define STRIP 49   // ceil(NN/1024)

typedef unsigned int u32;
typedef uint16_t u16;

__device__ __forceinline__ float b2f(u16 u){ return __builtin_bit_cast(float, (u32)((u32)u << 16)); }
__device__ __forceinline__ float b2f_lo(u32 p){ return __builtin_bit_cast(float, p << 16); }
__device__ __forceinline__ float b2f_hi(u32 p){ return __builtin_bit_cast(float, p & 0xffff0000u); }
__device__ __forceinline__ u32 f2b_bits(float f){ u32 u = __builtin_bit_cast(u32, f); return (u + 0x7fffu + ((u >> 16) & 1u)) >> 16; }
__device__ __forceinline__ u16 f2b(float f){ return (u16)f2b_bits(f); }
// RNE pack of 2 f32 -> bf16x2 in one instruction (same rounding as emulation)
__device__ __forceinline__ u32 packb(float lo, float hi){
  u32 r;
  asm("v_cvt_pk_bf16_f32 %0, %1, %2" : "=v"(r) : "v"(lo), "v"(hi));
  return r;
}

typedef __bf16 bf16x2 __attribute__((ext_vector_type(2)));
#if defined(__has_builtin)
#if __has_builtin(__builtin_amdgcn_fdot2_f32_bf16)
#define HAVE_DOT2_BUILTIN 1
#endif
#endif

#ifdef HAVE_DOT2_BUILTIN
__device__ __forceinline__ float dot2b(u32 a, u32 b, float c){
  return __builtin_amdgcn_fdot2_f32_bf16(__builtin_bit_cast(bf16x2, a),
                                         __builtin_bit_cast(bf16x2, b), c, false);
}
#else
__device__ __forceinline__ float dot2b(u32 a, u32 b, float c){
  c = fmaf(b2f_lo(a), b2f_lo(b), c);
  return fmaf(b2f_hi(a), b2f_hi(b), c);
}
#endif

// ---- MFMA plumbing ----
typedef __attribute__((ext_vector_type(8))) short short8;
typedef __attribute__((ext_vector_type(4))) float f32x4;
__device__ __forceinline__ f32x4 mf32(uint4 a, uint4 b, f32x4 c){
  return __builtin_amdgcn_mfma_f32_16x16x32_bf16(
      __builtin_bit_cast(short8, a), __builtin_bit_cast(short8, b), c, 0, 0, 0);
}

// channel permutation for 128-row weight blocks consumed as A-operands in two
// 16-row fragments/wave: stored row n -> actual channel. Makes each thread own
// 8 CONSECUTIVE channels (32*wv + 8*lq .. +7) across its two fragments.
__device__ __forceinline__ int chperm(int n){
  return 32 * ((n & 63) >> 4) + 8 * ((n & 15) >> 2) + 4 * (n >> 6) + (n & 3);
}

// pre-transposed weight layout offsets in u16 units (padded, zero-filled)
// Wang_* hold data at k in [16,32) (SH upper half of fused [EA|SH] operand).
// WANG_V/WANG_K/WLIN_V/W2_V rows are chperm-permuted.
#define OFF_WANG_V 0        // [128][40]
#define OFF_W1_V   5120     // [64][40]
#define OFF_WLIN_V 7680     // [128][136]
#define OFF_W2_V   25088    // [128][72]
#define OFF_WANG_K 34304    // [128][40]
#define OFF_W1_K   39424    // [64][40]
#define OFF_WLIN_K 41984    // [64][136]
#define OFF_W2_K   50688    // [64][72]
#define OFF_WOUT   55296    // [128][136]
#define OFF_WQD    72704    // [64][136]  (Wq @ blockdiag(Wdot))^T
#define WT_TOTAL   81408

__global__ __launch_bounds__(256) void zero_kernel(int* __restrict__ counts)
{
  int i = blockIdx.x * 256 + threadIdx.x;
  if (i < NN) counts[i] = 0;
}

// ---------------- one-time weight transpose/pad/bf16 prep
__global__ __launch_bounds__(256) void prep_w_kernel(
    const float* __restrict__ Wang_v, const float* __restrict__ W1_v,
    const float* __restrict__ Wlin_v, const float* __restrict__ W2_v,
    const float* __restrict__ Wang_k, const float* __restrict__ W1_k,
    const float* __restrict__ Wlin_k, const float* __restrict__ W2_k,
    const float* __restrict__ Wout, const float* __restrict__ Wq,
    const float* __restrict__ Wdot,
    u16* __restrict__ wt)
{
  int idx = blockIdx.x * 256 + threadIdx.x;
  if (idx >= WT_TOTAL) return;
  float val = 0.f;
  if (idx < OFF_W1_V) {
    int l = idx - OFF_WANG_V, n = l / 40, k = l % 40;
    if (k >= 16 && k < 32) val = Wang_v[chperm(n) * 16 + (k - 16)];
  } else if (idx < OFF_WLIN_V) {
    int l = idx - OFF_W1_V, n = l / 40, k = l % 40;
    if (k < 16) val = W1_v[k * 64 + n];
  } else if (idx < OFF_W2_V) {
    int l = idx - OFF_WLIN_V, n = l / 136, k = l % 136;
    if (k < 128) val = Wlin_v[k * 128 + chperm(n)];
  } else if (idx < OFF_WANG_K) {
    int l = idx - OFF_W2_V, n = l / 72, k = l % 72;
    if (k < 64) val = W2_v[k * 128 + chperm(n)];
  } else if (idx < OFF_W1_K) {
    int l = idx - OFF_WANG_K, n = l / 40, k = l % 40;
    if (k >= 16 && k < 32) val = Wang_k[chperm(n) * 16 + (k - 16)];
  } else if (idx < OFF_WLIN_K) {
    int l = idx - OFF_W1_K, n = l / 40, k = l % 40;
    if (k < 16) val = W1_k[k * 64 + n];
  } else if (idx < OFF_W2_K) {
    int l = idx - OFF_WLIN_K, n = l / 136, k = l % 136;
    if (k < 128) val = Wlin_k[k * 64 + n];
  } else if (idx < OFF_WOUT) {
    int l = idx - OFF_W2_K, n = l / 72, k = l % 72;
    if (k < 64) val = W2_k[k * 64 + n];
  } else if (idx < OFF_WQD) {                // WoutT: B^T[n][k] = Wout[k*128+n]
    int l = idx - OFF_WOUT, n = l / 136, k = l % 136;
    if (k < 128) val = Wout[k * 128 + n];
  } else {                                   // WqdT[n][k] = sum_i Wq[k,h*8+i]*Wdot[i,r]
    int l = idx - OFF_WQD, n = l / 136, k = l % 136;
    if (k < 128) {
      int h = n >> 3, r = n & 7;
      float s = 0.f;
#pragma unroll
      for (int i = 0; i < 8; ++i) s += Wq[k * 64 + h * 8 + i] * Wdot[i * 8 + r];
      val = s;
    }
  }
  wt[idx] = f2b(val);
}

// ---------------- qw = node_attr @ Wqd, MFMA, 64 nodes/block
__global__ __launch_bounds__(256) void qw_kernel(const float* __restrict__ node_attr,
                                                 const u16* __restrict__ wt,
                                                 u16* __restrict__ qw)
{
  __shared__ __align__(16) u16 sX[64 * 136];
  uint4* sX4 = (uint4*)sX;
  u32* sX32 = (u32*)sX;
  const uint4* wt4 = (const uint4*)wt;
  const int tid = threadIdx.x, wv = tid >> 6, lane = tid & 63, lq = lane >> 4, ln = lane & 15;
  const int n0 = blockIdx.x * 64;
  uint4 rB[4];
#pragma unroll
  for (int ks = 0; ks < 4; ++ks) rB[ks] = wt4[9088 + (wv * 16 + ln) * 17 + ks * 4 + lq];
  {
    int row = tid >> 2, q4 = tid & 3;
    int n = n0 + row;
    bool valid = n < NN;
    const float4* xp = (const float4*)(node_attr + (size_t)(valid ? n : 0) * 128);
#pragma unroll
    for (int i = 0; i < 8; ++i) {
      float4 v = valid ? xp[q4 * 8 + i] : make_float4(0.f, 0.f, 0.f, 0.f);
      sX32[row * 68 + (q4 * 8 + i) * 2]     = packb(v.x, v.y);
      sX32[row * 68 + (q4 * 8 + i) * 2 + 1] = packb(v.z, v.w);
    }
  }
  __syncthreads();
  const f32x4 z4 = {0.f, 0.f, 0.f, 0.f};
  int col = wv * 16 + ln;
#pragma unroll
  for (int et = 0; et < 4; ++et) {
    f32x4 acc = z4;
#pragma unroll
    for (int ks = 0; ks < 4; ++ks) acc = mf32(sX4[(et * 16 + ln) * 17 + ks * 4 + lq], rB[ks], acc);
#pragma unroll
    for (int r = 0; r < 4; ++r) {
      int rr = n0 + et * 16 + lq * 4 + r;
      if (rr < NN) qw[(size_t)rr * 64 + col] = f2b(acc[r]);
    }
  }
}

// ---------------- CSR build (runs BEFORE conv so conv can scatter-write in
// CSR order; downstream kernels then stream sequentially)
__global__ __launch_bounds__(256) void count_kernel(const int* __restrict__ edge_index,
                                                    int* __restrict__ counts)
{
  int e = blockIdx.x * 256 + threadIdx.x;
  if (e < NE) { int d = edge_index[NE + e]; if ((u32)d >= NN) d = 0; atomicAdd(&counts[d], 1); }
}

__global__ __launch_bounds__(1024) void scan_kernel(const int* __restrict__ counts,
                                                    int* __restrict__ row_ptr,
                                                    int* __restrict__ cursor)
{
  __shared__ int s[1024];
  int tid = threadIdx.x;
  int base = tid * STRIP;
  int sum = 0;
  for (int i = 0; i < STRIP; ++i) { int idx = base + i; sum += (idx < NN) ? counts[idx] : 0; }
  s[tid] = sum;
  __syncthreads();
  for (int off = 1; off < 1024; off <<= 1) {
    int v = s[tid];
    int add = (tid >= off) ? s[tid - off] : 0;
    __syncthreads();
    s[tid] = v + add;
    __syncthreads();
  }
  int running = (tid == 0) ? 0 : s[tid - 1];
  for (int i = 0; i < STRIP; ++i) {
    int idx = base + i;
    if (idx < NN) { row_ptr[idx] = running; cursor[idx] = running; running += counts[idx]; }
  }
  if (tid == 1023) row_ptr[NN] = running;
}

// produces edge_pos[e] = slot of edge e in CSR order
__global__ __launch_bounds__(256) void fill_kernel(const int* __restrict__ edge_index,
                                                   int* __restrict__ cursor,
                                                   int* __restrict__ edge_pos)
{
  int e = blockIdx.x * 256 + threadIdx.x;
  if (e < NE) {
    int dst = edge_index[NE + e]; if ((u32)dst >= NN) dst = 0;
    int pos = atomicAdd(&cursor[dst], 1);
    edge_pos[e] = ((u32)pos < NE) ? pos : 0;
  }
}

// ---------------- fused MFMA conv (single pass, swapped operands) + alpha.
// v and alpha are scatter-written at CSR position edge_pos[e].
__global__ __launch_bounds__(256, 2) void conv_fused_kernel(
    const float* __restrict__ node_attr, const float* __restrict__ edge_attr,
    const float* __restrict__ edge_sh, const int* __restrict__ edge_index,
    const float* __restrict__ b1v, const float* __restrict__ b1k,
    const u16* __restrict__ wt, const u16* __restrict__ qw,
    const int* __restrict__ edge_pos,
    u16* __restrict__ v_out, float* __restrict__ alpha)
{
  __shared__ __align__(16) u16 sC[64 * 40];    // fused [EA(16)|SH(16)|pad(8)]
  __shared__ __align__(16) u16 sX[64 * 136];   // t_v -> v result
  __shared__ __align__(16) u16 sTk[64 * 136];  // t_k
  __shared__ __align__(16) u16 sHv[64 * 72];   // relu(EA@W1v+b)
  __shared__ __align__(16) u16 sHk[64 * 72];   // relu(EA@W1k+b) -> k result
  uint4* sC4 = (uint4*)sC; u32* sC32 = (u32*)sC;
  uint4* sX4 = (uint4*)sX;
  uint4* sTk4 = (uint4*)sTk;
  uint4* sHv4 = (uint4*)sHv;
  uint4* sHk4 = (uint4*)sHk;
  const uint4* wt4 = (const uint4*)wt;

  const int tid = threadIdx.x;
  const int wv = tid >> 6, lane = tid & 63, lq = lane >> 4, ln = lane & 15;
  const int e0 = blockIdx.x * 64;
  const int nA = wv * 16 + ln, nB = (wv + 4) * 16 + ln;
  const int cb  = wv * 16 + 4 * lq;   // H-channel base (natural rows)
  const int cb8 = wv * 32 + 8 * lq;   // T-channel base (chperm rows)

  // dst q gather + CSR position early (latency hidden under staging/compute)
  const int el = tid >> 2, p = tid & 3;
  int dq = edge_index[NE + e0 + el]; if ((u32)dq >= NN) dq = 0;
  const uint4* qptr = (const uint4*)(qw + (size_t)dq * 64 + p * 16);
  uint4 q0 = qptr[0], q1 = qptr[1];
  int pos_el = edge_pos[e0 + el]; if ((u32)pos_el >= NE) pos_el = 0;

  // src indices for the 4 edges this thread computes in phase A
  int srcs[4];
#pragma unroll
  for (int et = 0; et < 4; ++et) {
    int s = edge_index[e0 + et * 16 + ln];
    if ((u32)s >= NN) s = 0;
    srcs[et] = s;
  }

  // phase-A weight fragments
  uint4 rW1V    = wt4[640 + nA * 5 + lq];
  uint4 rW1K    = wt4[4928 + nA * 5 + lq];
  uint4 rWangV0 = wt4[nA * 5 + lq],        rWangV1 = wt4[nB * 5 + lq];
  uint4 rWangK0 = wt4[4288 + nA * 5 + lq], rWangK1 = wt4[4288 + nB * 5 + lq];
  float4 bV = *(const float4*)(b1v + cb);
  float4 bK = *(const float4*)(b1k + cb);

  // stage fused EA|SH operand
  {
    int r = tid >> 2, kq = tid & 3;
    float4 ea = ((const float4*)(edge_attr + (size_t)(e0 + r) * 16))[kq];
    *(uint2*)(sC32 + r * 20 + kq * 2) = make_uint2(packb(ea.x, ea.y), packb(ea.z, ea.w));
    float4 sh = ((const float4*)(edge_sh + (size_t)(e0 + r) * 16))[kq];
    *(uint2*)(sC32 + r * 20 + 8 + kq * 2) = make_uint2(packb(sh.x, sh.y), packb(sh.z, sh.w));
  }
  // x prefetch for et=0 (channels cb8..cb8+7, f32, straight to regs)
  const float* xp0 = node_attr + (size_t)srcs[0] * 128 + cb8;
  float4 xa = *(const float4*)xp0;
  float4 xb = *(const float4*)(xp0 + 4);
  __syncthreads();   // S1

  const f32x4 z4 = {0.f, 0.f, 0.f, 0.f};
  // ---- phase A: radial MLP hidden + depthwise SH products
#pragma unroll
  for (int et = 0; et < 4; ++et) {
    float4 xa_n, xb_n;
    if (et < 3) {
      const float* xp = node_attr + (size_t)srcs[et + 1] * 128 + cb8;
      xa_n = *(const float4*)xp;
      xb_n = *(const float4*)(xp + 4);
    }
    uint4 aC = sC4[(et * 16 + ln) * 5 + lq];
    f32x4 hv  = mf32(rW1V, aC, z4);
    f32x4 hk  = mf32(rW1K, aC, z4);
    f32x4 t0v = mf32(rWangV0, aC, z4);
    f32x4 t1v = mf32(rWangV1, aC, z4);
    f32x4 t0k = mf32(rWangK0, aC, z4);
    f32x4 t1k = mf32(rWangK1, aC, z4);
    const int edge = et * 16 + ln;
    sX4[edge * 17 + 4 * wv + lq] = make_uint4(
        packb(t0v[0] * xa.x, t0v[1] * xa.y), packb(t0v[2] * xa.z, t0v[3] * xa.w),
        packb(t1v[0] * xb.x, t1v[1] * xb.y), packb(t1v[2] * xb.z, t1v[3] * xb.w));
    sTk4[edge * 17 + 4 * wv + lq] = make_uint4(
        packb(t0k[0] * xa.x, t0k[1] * xa.y), packb(t0k[2] * xa.z, t0k[3] * xa.w),
        packb(t1k[0] * xb.x, t1k[1] * xb.y), packb(t1k[2] * xb.z, t1k[3] * xb.w));
    *(uint2*)(sHv + edge * 72 + cb) = make_uint2(
        packb(fmaxf(hv[0] + bV.x, 0.f), fmaxf(hv[1] + bV.y, 0.f)),
        packb(fmaxf(hv[2] + bV.z, 0.f), fmaxf(hv[3] + bV.w, 0.f)));
    *(uint2*)(sHk + edge * 72 + cb) = make_uint2(
        packb(fmaxf(hk[0] + bK.x, 0.f), fmaxf(hk[1] + bK.y, 0.f)),
        packb(fmaxf(hk[2] + bK.z, 0.f), fmaxf(hk[3] + bK.w, 0.f)));
    xa = xa_n; xb = xb_n;
  }

  // phase-B weight fragments (issued here; in flight across the barrier)
  uint4 rWlinV[2][4], rWlinK[4], rW2V[2][2], rW2K[2];
#pragma unroll
  for (int ks = 0; ks < 4; ++ks) {
    rWlinV[0][ks] = wt4[960 + nA * 17 + ks * 4 + lq];
    rWlinV[1][ks] = wt4[960 + nB * 17 + ks * 4 + lq];
    rWlinK[ks]    = wt4[5248 + nA * 17 + ks * 4 + lq];
  }
#pragma unroll
  for (int ks = 0; ks < 2; ++ks) {
    rW2V[0][ks] = wt4[3136 + nA * 9 + ks * 4 + lq];
    rW2V[1][ks] = wt4[3136 + nB * 9 + ks * 4 + lq];
    rW2K[ks]    = wt4[6336 + nA * 9 + ks * 4 + lq];
  }
  __syncthreads();  // S2

  // ---- phase B: channel-mix (Wlin) and radial out (W2); results packed in regs
  uint4 pv[4]; uint2 pk[4];
#pragma unroll
  for (int et = 0; et < 4; ++et) {
    const int er = et * 16 + ln;
    f32x4 acc0 = z4, acc1 = z4, acck = z4;
#pragma unroll
    for (int ks = 0; ks < 4; ++ks) {
      uint4 tb = sX4[er * 17 + ks * 4 + lq];
      acc0 = mf32(rWlinV[0][ks], tb, acc0);
      acc1 = mf32(rWlinV[1][ks], tb, acc1);
      acck = mf32(rWlinK[ks], sTk4[er * 17 + ks * 4 + lq], acck);
    }
    f32x4 b0 = z4, b1 = z4, bk = z4;
#pragma unroll
    for (int ks = 0; ks < 2; ++ks) {
      uint4 hb = sHv4[er * 9 + ks * 4 + lq];
      b0 = mf32(rW2V[0][ks], hb, b0);
      b1 = mf32(rW2V[1][ks], hb, b1);
      bk = mf32(rW2K[ks], sHk4[er * 9 + ks * 4 + lq], bk);
    }
    pv[et] = make_uint4(packb(acc0[0] * b0[0], acc0[1] * b0[1]),
                        packb(acc0[2] * b0[2], acc0[3] * b0[3]),
                        packb(acc1[0] * b1[0], acc1[1] * b1[1]),
                        packb(acc1[2] * b1[2], acc1[3] * b1[3]));
    pk[et] = make_uint2(packb(acck[0] * bk[0], acck[1] * bk[1]),
                        packb(acck[2] * bk[2], acck[3] * bk[3]));
  }
  __syncthreads();  // S3

  // ---- result staging: v as b128 (channels cb8..cb8+7), k as b64
#pragma unroll
  for (int et = 0; et < 4; ++et) {
    const int edge = et * 16 + ln;
    sX4[edge * 17 + 4 * wv + lq] = pv[et];
    *(uint2*)(sHk + edge * 72 + cb) = pk[et];
  }
  __syncthreads();  // S4

  // v store, scattered to CSR slot (256B contiguous per edge; row==el)
  {
    int row = tid >> 2, seg = tid & 3;
    uint4* gp = (uint4*)(v_out + (size_t)pos_el * 128);
#pragma unroll
    for (int i = 0; i < 4; ++i) gp[seg * 4 + i] = sX4[row * 17 + seg * 4 + i];
  }
  // alpha = q . k  (bf16 dot2), scattered to CSR slot
  {
    uint4 k0 = sHk4[el * 9 + p * 2];
    uint4 k1 = sHk4[el * 9 + p * 2 + 1];
    float a0 = 0.f, a1 = 0.f;
    a0 = dot2b(q0.x, k0.x, a0); a0 = dot2b(q0.y, k0.y, a0);
    a0 = dot2b(q0.z, k0.z, a0); a0 = dot2b(q0.w, k0.w, a0);
    a1 = dot2b(q1.x, k1.x, a1); a1 = dot2b(q1.y, k1.y, a1);
    a1 = dot2b(q1.z, k1.z, a1); a1 = dot2b(q1.w, k1.w, a1);
    ((float2*)(alpha + (size_t)pos_el * 8))[p] = make_float2(a0, a1);
  }
}

// ---------------- per-node single-pass online softmax over SEQUENTIAL
// CSR-ordered alpha/v streams, 2-way split accumulators (halved rescale
// chain, flash-style merge) + MFMA @Wout epilogue. 16 nodes per block.
#define OUPD(mm_, ll_, aA_, aB_, aa, ww)                               \
  { float mn = fmaxf(mm_, (aa));                                       \
    float sc = __expf(mm_ - mn);                                       \
    float pw = __expf((aa) - mn);                                      \
    ll_ = ll_ * sc + pw;                                               \
    aA_ = aA_ * sc + pw * b2f_lo(ww);                                  \
    aB_ = aB_ * sc + pw * b2f_hi(ww);                                  \
    mm_ = mn; }

__global__ __launch_bounds__(256) void out_kernel(
    const int* __restrict__ row_ptr,
    const float* __restrict__ alpha, const u16* __restrict__ v_e,
    const u16* __restrict__ wt, float* __restrict__ out)
{
  __shared__ __align__(16) u16 sAgg[16 * 136];
  u32* sAgg32 = (u32*)sAgg;
  uint4* sAgg4 = (uint4*)sAgg;
  const uint4* wt4 = (const uint4*)wt;
  const u32* v32 = (const u32*)v_e;
  const int tid = threadIdx.x, wv = tid >> 6, lane = tid & 63, lq = lane >> 4, ln = lane & 15;
  const f32x4 z4 = {0.f, 0.f, 0.f, 0.f};
  uint4 rWT[2][4];
#pragma unroll
  for (int c = 0; c < 2; ++c) {
    int n = (wv * 2 + c) * 16 + ln;
#pragma unroll
    for (int ks = 0; ks < 4; ++ks) rWT[c][ks] = wt4[6912 + n * 17 + ks * 4 + lq];
  }
  const int hh = lane >> 3;   // head of cols {2*lane, 2*lane+1}
  const int grp = blockIdx.x;
#pragma unroll 1
  for (int i = 0; i < 4; ++i) {
    int n = grp * 16 + wv * 4 + i;
    int beg = row_ptr[n], end = row_ptr[n + 1];
    if (beg < 0) beg = 0; if (beg > NE) beg = NE;
    if (end < beg) end = beg; if (end > NE) end = NE;
    int deg = end - beg;
    float m0 = -3.0e38f, l0 = 0.f, a0A = 0.f, a0B = 0.f;
    float m1 = -3.0e38f, l1 = 0.f, a1A = 0.f, a1B = 0.f;
    int j = 0;
#pragma unroll 1
    for (; j + 4 <= deg; j += 4) {
      size_t b = (size_t)(beg + j);
      float aa0 = alpha[(b)     * 8 + hh]; u32 w0 = v32[(b)     * 64 + lane];
      float aa1 = alpha[(b + 1) * 8 + hh]; u32 w1 = v32[(b + 1) * 64 + lane];
      float aa2 = alpha[(b + 2) * 8 + hh]; u32 w2 = v32[(b + 2) * 64 + lane];
      float aa3 = alpha[(b + 3) * 8 + hh]; u32 w3 = v32[(b + 3) * 64 + lane];
      OUPD(m0, l0, a0A, a0B, aa0, w0);
      OUPD(m1, l1, a1A, a1B, aa1, w1);
      OUPD(m0, l0, a0A, a0B, aa2, w2);
      OUPD(m1, l1, a1A, a1B, aa3, w3);
    }
#pragma unroll 1
    for (; j < deg; ++j) {
      size_t b = (size_t)(beg + j);
      float aa = alpha[b * 8 + hh]; u32 w = v32[b * 64 + lane];
      OUPD(m0, l0, a0A, a0B, aa, w);
    }
    // flash-style merge of the two partial softmax states
    float mm = fmaxf(m0, m1);
    float s0 = __expf(m0 - mm), s1 = __expf(m1 - mm);
    float l = l0 * s0 + l1 * s1;
    float accA = a0A * s0 + a1A * s1;
    float accB = a0B * s0 + a1B * s1;
    float inv = (l > 0.f) ? (1.f / l) : 0.f;
    accA *= inv; accB *= inv;
    sAgg32[(wv * 4 + i) * 68 + lane] = packb(accA, accB);
  }
  __syncthreads();
#pragma unroll
  for (int c = 0; c < 2; ++c) {
    f32x4 acc = z4;
#pragma unroll
    for (int ks = 0; ks < 4; ++ks) acc = mf32(sAgg4[ln * 17 + ks * 4 + lq], rWT[c][ks], acc);
    int col = (wv * 2 + c) * 16 + ln;
#pragma unroll
    for (int r = 0; r < 4; ++r)
      out[(size_t)(grp * 16 + lq * 4 + r) * 128 + col] = acc[r];
  }
}

extern "C" void kernel_launch(void* const* d_in, const int* in_sizes, int n_in,
                              void* d_out, int out_size, void* d_ws, size_t ws_size,
                              hipStream_t stream)
{
  const float* node_attr = (const float*)d_in[0];
  const float* edge_attr = (const float*)d_in[1];
  const float* edge_sh   = (const float*)d_in[2];
  const float* Wq        = (const float*)d_in[3];
  const float* Wang_k    = (const float*)d_in[4];
  const float* Wlin_k    = (const float*)d_in[5];
  const float* W1k       = (const float*)d_in[6];
  const float* b1k       = (const float*)d_in[7];
  const float* W2k       = (const float*)d_in[8];
  const float* Wang_v    = (const float*)d_in[9];
  const float* Wlin_v    = (const float*)d_in[10];
  const float* W1v       = (const float*)d_in[11];
  const float* b1v       = (const float*)d_in[12];
  const float* W2v       = (const float*)d_in[13];
  const float* Wdot      = (const float*)d_in[14];
  const float* Wout      = (const float*)d_in[15];
  const int* edge_index  = (const int*)d_in[16];
  float* out = (float*)d_out;

  char* ws = (char*)d_ws;
  u16*   v_e      = (u16*)(ws + 0);                 // E*128*2  = 204,800,000 (CSR order)
  float* alpha    = (float*)(ws + 204800000);       // E*8*4    =  25,600,000 (CSR order)
  u16*   qw       = (u16*)(ws + 230400000);         // N*64*2   =   6,400,000
  int*   counts   = (int*)(ws + 236800000);         // 200,064
  int*   row_ptr  = (int*)(ws + 237000064);         // 200,064
  int*   cursor   = (int*)(ws + 237200128);         // 200,064
  int*   edge_pos = (int*)(ws + 237400192);         // 3,200,000
  u16*   wt       = (u16*)(ws + 240600192);         // 162,816 -> total 240,763,008

  zero_kernel<<<dim3((NN + 255) / 256), dim3(256), 0, stream>>>(counts);
  prep_w_kernel<<<dim3((WT_TOTAL + 255) / 256), dim3(256), 0, stream>>>(
      Wang_v, W1v, Wlin_v, W2v, Wang_k, W1k, Wlin_k, W2k, Wout, Wq, Wdot, wt);
  qw_kernel<<<dim3((NN + 63) / 64), dim3(256), 0, stream>>>(node_attr, wt, qw);
  count_kernel<<<dim3((NE + 255) / 256), dim3(256), 0, stream>>>(edge_index, counts);
  scan_kernel<<<dim3(1), dim3(1024), 0, stream>>>(counts, row_ptr, cursor);
  fill_kernel<<<dim3((NE + 255) / 256), dim3(256), 0, stream>>>(edge_index, cursor, edge_pos);
  conv_fused_kernel<<<dim3(NE / 64), dim3(256), 0, stream>>>(
      node_attr, edge_attr, edge_sh, edge_index, b1v, b1k, wt, qw, edge_pos, v_e, alpha);
  out_kernel<<<dim3(3125), dim3(256), 0, stream>>>(row_ptr, alpha, v_e, wt, out);
}

// Round 12
// 574.044 us; speedup vs baseline: 1.1168x; 1.1168x over previous
//
#include <hip/hip_runtime.h>
#include <stdint.h>

#define NN 50000
#define NE 800000
#define STRIP 49   // ceil(NN/1024)

typedef unsigned int u32;
typedef uint16_t u16;

__device__ __forceinline__ float b2f(u16 u){ return __builtin_bit_cast(float, (u32)((u32)u << 16)); }
__device__ __forceinline__ float b2f_lo(u32 p){ return __builtin_bit_cast(float, p << 16); }
__device__ __forceinline__ float b2f_hi(u32 p){ return __builtin_bit_cast(float, p & 0xffff0000u); }
__device__ __forceinline__ u32 f2b_bits(float f){ u32 u = __builtin_bit_cast(u32, f); return (u + 0x7fffu + ((u >> 16) & 1u)) >> 16; }
__device__ __forceinline__ u16 f2b(float f){ return (u16)f2b_bits(f); }
// RNE pack of 2 f32 -> bf16x2 in one instruction (same rounding as emulation)
__device__ __forceinline__ u32 packb(float lo, float hi){
  u32 r;
  asm("v_cvt_pk_bf16_f32 %0, %1, %2" : "=v"(r) : "v"(lo), "v"(hi));
  return r;
}

typedef __bf16 bf16x2 __attribute__((ext_vector_type(2)));
#if defined(__has_builtin)
#if __has_builtin(__builtin_amdgcn_fdot2_f32_bf16)
#define HAVE_DOT2_BUILTIN 1
#endif
#endif

#ifdef HAVE_DOT2_BUILTIN
__device__ __forceinline__ float dot2b(u32 a, u32 b, float c){
  return __builtin_amdgcn_fdot2_f32_bf16(__builtin_bit_cast(bf16x2, a),
                                         __builtin_bit_cast(bf16x2, b), c, false);
}
#else
__device__ __forceinline__ float dot2b(u32 a, u32 b, float c){
  c = fmaf(b2f_lo(a), b2f_lo(b), c);
  return fmaf(b2f_hi(a), b2f_hi(b), c);
}
#endif

// ---- MFMA plumbing ----
typedef __attribute__((ext_vector_type(8))) short short8;
typedef __attribute__((ext_vector_type(4))) float f32x4;
__device__ __forceinline__ f32x4 mf32(uint4 a, uint4 b, f32x4 c){
  return __builtin_amdgcn_mfma_f32_16x16x32_bf16(
      __builtin_bit_cast(short8, a), __builtin_bit_cast(short8, b), c, 0, 0, 0);
}

// channel permutation for 128-row weight blocks consumed as A-operands in two
// 16-row fragments/wave: stored row n -> actual channel. Makes each thread own
// 8 CONSECUTIVE channels (32*wv + 8*lq .. +7) across its two fragments.
__device__ __forceinline__ int chperm(int n){
  return 32 * ((n & 63) >> 4) + 8 * ((n & 15) >> 2) + 4 * (n >> 6) + (n & 3);
}

// pre-transposed weight layout offsets in u16 units (padded, zero-filled)
// Wang_* hold data at k in [16,32) (SH upper half of fused [EA|SH] operand).
// WANG_V/WANG_K/WLIN_V/W2_V rows are chperm-permuted.
#define OFF_WANG_V 0        // [128][40]
#define OFF_W1_V   5120     // [64][40]
#define OFF_WLIN_V 7680     // [128][136]
#define OFF_W2_V   25088    // [128][72]
#define OFF_WANG_K 34304    // [128][40]
#define OFF_W1_K   39424    // [64][40]
#define OFF_WLIN_K 41984    // [64][136]
#define OFF_W2_K   50688    // [64][72]
#define OFF_WOUT   55296    // [128][136]
#define OFF_WQD    72704    // [64][136]  (Wq @ blockdiag(Wdot))^T
#define WT_TOTAL   81408

__global__ __launch_bounds__(256) void zero_kernel(int* __restrict__ counts)
{
  int i = blockIdx.x * 256 + threadIdx.x;
  if (i < NN) counts[i] = 0;
}

// ---------------- one-time weight transpose/pad/bf16 prep
__global__ __launch_bounds__(256) void prep_w_kernel(
    const float* __restrict__ Wang_v, const float* __restrict__ W1_v,
    const float* __restrict__ Wlin_v, const float* __restrict__ W2_v,
    const float* __restrict__ Wang_k, const float* __restrict__ W1_k,
    const float* __restrict__ Wlin_k, const float* __restrict__ W2_k,
    const float* __restrict__ Wout, const float* __restrict__ Wq,
    const float* __restrict__ Wdot,
    u16* __restrict__ wt)
{
  int idx = blockIdx.x * 256 + threadIdx.x;
  if (idx >= WT_TOTAL) return;
  float val = 0.f;
  if (idx < OFF_W1_V) {
    int l = idx - OFF_WANG_V, n = l / 40, k = l % 40;
    if (k >= 16 && k < 32) val = Wang_v[chperm(n) * 16 + (k - 16)];
  } else if (idx < OFF_WLIN_V) {
    int l = idx - OFF_W1_V, n = l / 40, k = l % 40;
    if (k < 16) val = W1_v[k * 64 + n];
  } else if (idx < OFF_W2_V) {
    int l = idx - OFF_WLIN_V, n = l / 136, k = l % 136;
    if (k < 128) val = Wlin_v[k * 128 + chperm(n)];
  } else if (idx < OFF_WANG_K) {
    int l = idx - OFF_W2_V, n = l / 72, k = l % 72;
    if (k < 64) val = W2_v[k * 128 + chperm(n)];
  } else if (idx < OFF_W1_K) {
    int l = idx - OFF_WANG_K, n = l / 40, k = l % 40;
    if (k >= 16 && k < 32) val = Wang_k[chperm(n) * 16 + (k - 16)];
  } else if (idx < OFF_WLIN_K) {
    int l = idx - OFF_W1_K, n = l / 40, k = l % 40;
    if (k < 16) val = W1_k[k * 64 + n];
  } else if (idx < OFF_W2_K) {
    int l = idx - OFF_WLIN_K, n = l / 136, k = l % 136;
    if (k < 128) val = Wlin_k[k * 64 + n];
  } else if (idx < OFF_WOUT) {
    int l = idx - OFF_W2_K, n = l / 72, k = l % 72;
    if (k < 64) val = W2_k[k * 64 + n];
  } else if (idx < OFF_WQD) {                // WoutT: B^T[n][k] = Wout[k*128+n]
    int l = idx - OFF_WOUT, n = l / 136, k = l % 136;
    if (k < 128) val = Wout[k * 128 + n];
  } else {                                   // WqdT[n][k] = sum_i Wq[k,h*8+i]*Wdot[i,r]
    int l = idx - OFF_WQD, n = l / 136, k = l % 136;
    if (k < 128) {
      int h = n >> 3, r = n & 7;
      float s = 0.f;
#pragma unroll
      for (int i = 0; i < 8; ++i) s += Wq[k * 64 + h * 8 + i] * Wdot[i * 8 + r];
      val = s;
    }
  }
  wt[idx] = f2b(val);
}

// ---------------- qw = node_attr @ Wqd, MFMA, 64 nodes/block
__global__ __launch_bounds__(256) void qw_kernel(const float* __restrict__ node_attr,
                                                 const u16* __restrict__ wt,
                                                 u16* __restrict__ qw)
{
  __shared__ __align__(16) u16 sX[64 * 136];
  uint4* sX4 = (uint4*)sX;
  u32* sX32 = (u32*)sX;
  const uint4* wt4 = (const uint4*)wt;
  const int tid = threadIdx.x, wv = tid >> 6, lane = tid & 63, lq = lane >> 4, ln = lane & 15;
  const int n0 = blockIdx.x * 64;
  uint4 rB[4];
#pragma unroll
  for (int ks = 0; ks < 4; ++ks) rB[ks] = wt4[9088 + (wv * 16 + ln) * 17 + ks * 4 + lq];
  {
    int row = tid >> 2, q4 = tid & 3;
    int n = n0 + row;
    bool valid = n < NN;
    const float4* xp = (const float4*)(node_attr + (size_t)(valid ? n : 0) * 128);
#pragma unroll
    for (int i = 0; i < 8; ++i) {
      float4 v = valid ? xp[q4 * 8 + i] : make_float4(0.f, 0.f, 0.f, 0.f);
      sX32[row * 68 + (q4 * 8 + i) * 2]     = packb(v.x, v.y);
      sX32[row * 68 + (q4 * 8 + i) * 2 + 1] = packb(v.z, v.w);
    }
  }
  __syncthreads();
  const f32x4 z4 = {0.f, 0.f, 0.f, 0.f};
  int col = wv * 16 + ln;
#pragma unroll
  for (int et = 0; et < 4; ++et) {
    f32x4 acc = z4;
#pragma unroll
    for (int ks = 0; ks < 4; ++ks) acc = mf32(sX4[(et * 16 + ln) * 17 + ks * 4 + lq], rB[ks], acc);
#pragma unroll
    for (int r = 0; r < 4; ++r) {
      int rr = n0 + et * 16 + lq * 4 + r;
      if (rr < NN) qw[(size_t)rr * 64 + col] = f2b(acc[r]);
    }
  }
}

// ---------------- CSR build. count_kernel also records each edge's
// within-segment rank (the atomic's return value) so edge_pos[e] =
// row_ptr[dst] + edge_rel[e] is later PURE ARITHMETIC (fill_kernel deleted).
__global__ __launch_bounds__(256) void count_kernel(const int* __restrict__ edge_index,
                                                    int* __restrict__ counts,
                                                    int* __restrict__ edge_rel)
{
  int e = blockIdx.x * 256 + threadIdx.x;
  if (e < NE) {
    int d = edge_index[NE + e]; if ((u32)d >= NN) d = 0;
    edge_rel[e] = atomicAdd(&counts[d], 1);
  }
}

__global__ __launch_bounds__(1024) void scan_kernel(const int* __restrict__ counts,
                                                    int* __restrict__ row_ptr)
{
  __shared__ int s[1024];
  int tid = threadIdx.x;
  int base = tid * STRIP;
  int sum = 0;
  for (int i = 0; i < STRIP; ++i) { int idx = base + i; sum += (idx < NN) ? counts[idx] : 0; }
  s[tid] = sum;
  __syncthreads();
  for (int off = 1; off < 1024; off <<= 1) {
    int v = s[tid];
    int add = (tid >= off) ? s[tid - off] : 0;
    __syncthreads();
    s[tid] = v + add;
    __syncthreads();
  }
  int running = (tid == 0) ? 0 : s[tid - 1];
  for (int i = 0; i < STRIP; ++i) {
    int idx = base + i;
    if (idx < NN) { row_ptr[idx] = running; running += counts[idx]; }
  }
  if (tid == 1023) row_ptr[NN] = running;
}

// ---------------- fused MFMA conv (single pass, swapped operands) + alpha.
// v and alpha scatter-written at CSR position row_ptr[dst] + edge_rel[e]
// (no atomics, no fill kernel).
__global__ __launch_bounds__(256, 2) void conv_fused_kernel(
    const float* __restrict__ node_attr, const float* __restrict__ edge_attr,
    const float* __restrict__ edge_sh, const int* __restrict__ edge_index,
    const float* __restrict__ b1v, const float* __restrict__ b1k,
    const u16* __restrict__ wt, const u16* __restrict__ qw,
    const int* __restrict__ row_ptr, const int* __restrict__ edge_rel,
    u16* __restrict__ v_out, float* __restrict__ alpha)
{
  __shared__ __align__(16) u16 sC[64 * 40];    // fused [EA(16)|SH(16)|pad(8)]
  __shared__ __align__(16) u16 sX[64 * 136];   // t_v -> v result
  __shared__ __align__(16) u16 sTk[64 * 136];  // t_k
  __shared__ __align__(16) u16 sHv[64 * 72];   // relu(EA@W1v+b)
  __shared__ __align__(16) u16 sHk[64 * 72];   // relu(EA@W1k+b) -> k result
  uint4* sC4 = (uint4*)sC; u32* sC32 = (u32*)sC;
  uint4* sX4 = (uint4*)sX;
  uint4* sTk4 = (uint4*)sTk;
  uint4* sHv4 = (uint4*)sHv;
  uint4* sHk4 = (uint4*)sHk;
  const uint4* wt4 = (const uint4*)wt;

  const int tid = threadIdx.x;
  const int wv = tid >> 6, lane = tid & 63, lq = lane >> 4, ln = lane & 15;
  const int e0 = blockIdx.x * 64;
  const int nA = wv * 16 + ln, nB = (wv + 4) * 16 + ln;
  const int cb  = wv * 16 + 4 * lq;   // H-channel base (natural rows)
  const int cb8 = wv * 32 + 8 * lq;   // T-channel base (chperm rows)

  // dst q gather + CSR position (arithmetic from row_ptr + rel) early
  const int el = tid >> 2, p = tid & 3;
  int dq = edge_index[NE + e0 + el]; if ((u32)dq >= NN) dq = 0;
  const uint4* qptr = (const uint4*)(qw + (size_t)dq * 64 + p * 16);
  uint4 q0 = qptr[0], q1 = qptr[1];
  int pos_el = row_ptr[dq] + edge_rel[e0 + el];
  if ((u32)pos_el >= NE) pos_el = 0;

  // src indices for the 4 edges this thread computes in phase A
  int srcs[4];
#pragma unroll
  for (int et = 0; et < 4; ++et) {
    int s = edge_index[e0 + et * 16 + ln];
    if ((u32)s >= NN) s = 0;
    srcs[et] = s;
  }

  // phase-A weight fragments
  uint4 rW1V    = wt4[640 + nA * 5 + lq];
  uint4 rW1K    = wt4[4928 + nA * 5 + lq];
  uint4 rWangV0 = wt4[nA * 5 + lq],        rWangV1 = wt4[nB * 5 + lq];
  uint4 rWangK0 = wt4[4288 + nA * 5 + lq], rWangK1 = wt4[4288 + nB * 5 + lq];
  float4 bV = *(const float4*)(b1v + cb);
  float4 bK = *(const float4*)(b1k + cb);

  // stage fused EA|SH operand
  {
    int r = tid >> 2, kq = tid & 3;
    float4 ea = ((const float4*)(edge_attr + (size_t)(e0 + r) * 16))[kq];
    *(uint2*)(sC32 + r * 20 + kq * 2) = make_uint2(packb(ea.x, ea.y), packb(ea.z, ea.w));
    float4 sh = ((const float4*)(edge_sh + (size_t)(e0 + r) * 16))[kq];
    *(uint2*)(sC32 + r * 20 + 8 + kq * 2) = make_uint2(packb(sh.x, sh.y), packb(sh.z, sh.w));
  }
  // x prefetch for et=0 (channels cb8..cb8+7, f32, straight to regs)
  const float* xp0 = node_attr + (size_t)srcs[0] * 128 + cb8;
  float4 xa = *(const float4*)xp0;
  float4 xb = *(const float4*)(xp0 + 4);
  __syncthreads();   // S1

  const f32x4 z4 = {0.f, 0.f, 0.f, 0.f};
  // ---- phase A: radial MLP hidden + depthwise SH products
#pragma unroll
  for (int et = 0; et < 4; ++et) {
    float4 xa_n, xb_n;
    if (et < 3) {
      const float* xp = node_attr + (size_t)srcs[et + 1] * 128 + cb8;
      xa_n = *(const float4*)xp;
      xb_n = *(const float4*)(xp + 4);
    }
    uint4 aC = sC4[(et * 16 + ln) * 5 + lq];
    f32x4 hv  = mf32(rW1V, aC, z4);
    f32x4 hk  = mf32(rW1K, aC, z4);
    f32x4 t0v = mf32(rWangV0, aC, z4);
    f32x4 t1v = mf32(rWangV1, aC, z4);
    f32x4 t0k = mf32(rWangK0, aC, z4);
    f32x4 t1k = mf32(rWangK1, aC, z4);
    const int edge = et * 16 + ln;
    sX4[edge * 17 + 4 * wv + lq] = make_uint4(
        packb(t0v[0] * xa.x, t0v[1] * xa.y), packb(t0v[2] * xa.z, t0v[3] * xa.w),
        packb(t1v[0] * xb.x, t1v[1] * xb.y), packb(t1v[2] * xb.z, t1v[3] * xb.w));
    sTk4[edge * 17 + 4 * wv + lq] = make_uint4(
        packb(t0k[0] * xa.x, t0k[1] * xa.y), packb(t0k[2] * xa.z, t0k[3] * xa.w),
        packb(t1k[0] * xb.x, t1k[1] * xb.y), packb(t1k[2] * xb.z, t1k[3] * xb.w));
    *(uint2*)(sHv + edge * 72 + cb) = make_uint2(
        packb(fmaxf(hv[0] + bV.x, 0.f), fmaxf(hv[1] + bV.y, 0.f)),
        packb(fmaxf(hv[2] + bV.z, 0.f), fmaxf(hv[3] + bV.w, 0.f)));
    *(uint2*)(sHk + edge * 72 + cb) = make_uint2(
        packb(fmaxf(hk[0] + bK.x, 0.f), fmaxf(hk[1] + bK.y, 0.f)),
        packb(fmaxf(hk[2] + bK.z, 0.f), fmaxf(hk[3] + bK.w, 0.f)));
    xa = xa_n; xb = xb_n;
  }

  // phase-B weight fragments (issued here; in flight across the barrier)
  uint4 rWlinV[2][4], rWlinK[4], rW2V[2][2], rW2K[2];
#pragma unroll
  for (int ks = 0; ks < 4; ++ks) {
    rWlinV[0][ks] = wt4[960 + nA * 17 + ks * 4 + lq];
    rWlinV[1][ks] = wt4[960 + nB * 17 + ks * 4 + lq];
    rWlinK[ks]    = wt4[5248 + nA * 17 + ks * 4 + lq];
  }
#pragma unroll
  for (int ks = 0; ks < 2; ++ks) {
    rW2V[0][ks] = wt4[3136 + nA * 9 + ks * 4 + lq];
    rW2V[1][ks] = wt4[3136 + nB * 9 + ks * 4 + lq];
    rW2K[ks]    = wt4[6336 + nA * 9 + ks * 4 + lq];
  }
  __syncthreads();  // S2

  // ---- phase B: channel-mix (Wlin) and radial out (W2); results packed in regs
  uint4 pv[4]; uint2 pk[4];
#pragma unroll
  for (int et = 0; et < 4; ++et) {
    const int er = et * 16 + ln;
    f32x4 acc0 = z4, acc1 = z4, acck = z4;
#pragma unroll
    for (int ks = 0; ks < 4; ++ks) {
      uint4 tb = sX4[er * 17 + ks * 4 + lq];
      acc0 = mf32(rWlinV[0][ks], tb, acc0);
      acc1 = mf32(rWlinV[1][ks], tb, acc1);
      acck = mf32(rWlinK[ks], sTk4[er * 17 + ks * 4 + lq], acck);
    }
    f32x4 b0 = z4, b1 = z4, bk = z4;
#pragma unroll
    for (int ks = 0; ks < 2; ++ks) {
      uint4 hb = sHv4[er * 9 + ks * 4 + lq];
      b0 = mf32(rW2V[0][ks], hb, b0);
      b1 = mf32(rW2V[1][ks], hb, b1);
      bk = mf32(rW2K[ks], sHk4[er * 9 + ks * 4 + lq], bk);
    }
    pv[et] = make_uint4(packb(acc0[0] * b0[0], acc0[1] * b0[1]),
                        packb(acc0[2] * b0[2], acc0[3] * b0[3]),
                        packb(acc1[0] * b1[0], acc1[1] * b1[1]),
                        packb(acc1[2] * b1[2], acc1[3] * b1[3]));
    pk[et] = make_uint2(packb(acck[0] * bk[0], acck[1] * bk[1]),
                        packb(acck[2] * bk[2], acck[3] * bk[3]));
  }
  __syncthreads();  // S3

  // ---- result staging: v as b128 (channels cb8..cb8+7), k as b64
#pragma unroll
  for (int et = 0; et < 4; ++et) {
    const int edge = et * 16 + ln;
    sX4[edge * 17 + 4 * wv + lq] = pv[et];
    *(uint2*)(sHk + edge * 72 + cb) = pk[et];
  }
  __syncthreads();  // S4

  // v store, scattered to CSR slot (256B contiguous per edge; row==el)
  {
    int row = tid >> 2, seg = tid & 3;
    uint4* gp = (uint4*)(v_out + (size_t)pos_el * 128);
#pragma unroll
    for (int i = 0; i < 4; ++i) gp[seg * 4 + i] = sX4[row * 17 + seg * 4 + i];
  }
  // alpha = q . k  (bf16 dot2), scattered to CSR slot
  {
    uint4 k0 = sHk4[el * 9 + p * 2];
    uint4 k1 = sHk4[el * 9 + p * 2 + 1];
    float a0 = 0.f, a1 = 0.f;
    a0 = dot2b(q0.x, k0.x, a0); a0 = dot2b(q0.y, k0.y, a0);
    a0 = dot2b(q0.z, k0.z, a0); a0 = dot2b(q0.w, k0.w, a0);
    a1 = dot2b(q1.x, k1.x, a1); a1 = dot2b(q1.y, k1.y, a1);
    a1 = dot2b(q1.z, k1.z, a1); a1 = dot2b(q1.w, k1.w, a1);
    ((float2*)(alpha + (size_t)pos_el * 8))[p] = make_float2(a0, a1);
  }
}

// ---------------- per-node single-pass online softmax over SEQUENTIAL
// CSR-ordered alpha/v streams, 2-way split accumulators (halved rescale
// chain, flash-style merge) + MFMA @Wout epilogue. 16 nodes per block.
#define OUPD(mm_, ll_, aA_, aB_, aa, ww)                               \
  { float mn = fmaxf(mm_, (aa));                                       \
    float sc = __expf(mm_ - mn);                                       \
    float pw = __expf((aa) - mn);                                      \
    ll_ = ll_ * sc + pw;                                               \
    aA_ = aA_ * sc + pw * b2f_lo(ww);                                  \
    aB_ = aB_ * sc + pw * b2f_hi(ww);                                  \
    mm_ = mn; }

__global__ __launch_bounds__(256) void out_kernel(
    const int* __restrict__ row_ptr,
    const float* __restrict__ alpha, const u16* __restrict__ v_e,
    const u16* __restrict__ wt, float* __restrict__ out)
{
  __shared__ __align__(16) u16 sAgg[16 * 136];
  u32* sAgg32 = (u32*)sAgg;
  uint4* sAgg4 = (uint4*)sAgg;
  const uint4* wt4 = (const uint4*)wt;
  const u32* v32 = (const u32*)v_e;
  const int tid = threadIdx.x, wv = tid >> 6, lane = tid & 63, lq = lane >> 4, ln = lane & 15;
  const f32x4 z4 = {0.f, 0.f, 0.f, 0.f};
  uint4 rWT[2][4];
#pragma unroll
  for (int c = 0; c < 2; ++c) {
    int n = (wv * 2 + c) * 16 + ln;
#pragma unroll
    for (int ks = 0; ks < 4; ++ks) rWT[c][ks] = wt4[6912 + n * 17 + ks * 4 + lq];
  }
  const int hh = lane >> 3;   // head of cols {2*lane, 2*lane+1}
  const int grp = blockIdx.x;
#pragma unroll 1
  for (int i = 0; i < 4; ++i) {
    int n = grp * 16 + wv * 4 + i;
    int beg = row_ptr[n], end = row_ptr[n + 1];
    if (beg < 0) beg = 0; if (beg > NE) beg = NE;
    if (end < beg) end = beg; if (end > NE) end = NE;
    int deg = end - beg;
    float m0 = -3.0e38f, l0 = 0.f, a0A = 0.f, a0B = 0.f;
    float m1 = -3.0e38f, l1 = 0.f, a1A = 0.f, a1B = 0.f;
    int j = 0;
#pragma unroll 1
    for (; j + 4 <= deg; j += 4) {
      size_t b = (size_t)(beg + j);
      float aa0 = alpha[(b)     * 8 + hh]; u32 w0 = v32[(b)     * 64 + lane];
      float aa1 = alpha[(b + 1) * 8 + hh]; u32 w1 = v32[(b + 1) * 64 + lane];
      float aa2 = alpha[(b + 2) * 8 + hh]; u32 w2 = v32[(b + 2) * 64 + lane];
      float aa3 = alpha[(b + 3) * 8 + hh]; u32 w3 = v32[(b + 3) * 64 + lane];
      OUPD(m0, l0, a0A, a0B, aa0, w0);
      OUPD(m1, l1, a1A, a1B, aa1, w1);
      OUPD(m0, l0, a0A, a0B, aa2, w2);
      OUPD(m1, l1, a1A, a1B, aa3, w3);
    }
#pragma unroll 1
    for (; j < deg; ++j) {
      size_t b = (size_t)(beg + j);
      float aa = alpha[b * 8 + hh]; u32 w = v32[b * 64 + lane];
      OUPD(m0, l0, a0A, a0B, aa, w);
    }
    // flash-style merge of the two partial softmax states
    float mm = fmaxf(m0, m1);
    float s0 = __expf(m0 - mm), s1 = __expf(m1 - mm);
    float l = l0 * s0 + l1 * s1;
    float accA = a0A * s0 + a1A * s1;
    float accB = a0B * s0 + a1B * s1;
    float inv = (l > 0.f) ? (1.f / l) : 0.f;
    accA *= inv; accB *= inv;
    sAgg32[(wv * 4 + i) * 68 + lane] = packb(accA, accB);
  }
  __syncthreads();
#pragma unroll
  for (int c = 0; c < 2; ++c) {
    f32x4 acc = z4;
#pragma unroll
    for (int ks = 0; ks < 4; ++ks) acc = mf32(sAgg4[ln * 17 + ks * 4 + lq], rWT[c][ks], acc);
    int col = (wv * 2 + c) * 16 + ln;
#pragma unroll
    for (int r = 0; r < 4; ++r)
      out[(size_t)(grp * 16 + lq * 4 + r) * 128 + col] = acc[r];
  }
}

extern "C" void kernel_launch(void* const* d_in, const int* in_sizes, int n_in,
                              void* d_out, int out_size, void* d_ws, size_t ws_size,
                              hipStream_t stream)
{
  const float* node_attr = (const float*)d_in[0];
  const float* edge_attr = (const float*)d_in[1];
  const float* edge_sh   = (const float*)d_in[2];
  const float* Wq        = (const float*)d_in[3];
  const float* Wang_k    = (const float*)d_in[4];
  const float* Wlin_k    = (const float*)d_in[5];
  const float* W1k       = (const float*)d_in[6];
  const float* b1k       = (const float*)d_in[7];
  const float* W2k       = (const float*)d_in[8];
  const float* Wang_v    = (const float*)d_in[9];
  const float* Wlin_v    = (const float*)d_in[10];
  const float* W1v       = (const float*)d_in[11];
  const float* b1v       = (const float*)d_in[12];
  const float* W2v       = (const float*)d_in[13];
  const float* Wdot      = (const float*)d_in[14];
  const float* Wout      = (const float*)d_in[15];
  const int* edge_index  = (const int*)d_in[16];
  float* out = (float*)d_out;

  char* ws = (char*)d_ws;
  u16*   v_e      = (u16*)(ws + 0);                 // E*128*2  = 204,800,000 (CSR order)
  float* alpha    = (float*)(ws + 204800000);       // E*8*4    =  25,600,000 (CSR order)
  u16*   qw       = (u16*)(ws + 230400000);         // N*64*2   =   6,400,000
  int*   counts   = (int*)(ws + 236800000);         // 200,064
  int*   row_ptr  = (int*)(ws + 237000064);         // 200,064
  int*   edge_rel = (int*)(ws + 237400192);         // 3,200,000 (within-segment rank)
  u16*   wt       = (u16*)(ws + 240600192);         // 162,816 -> total 240,763,008

  zero_kernel<<<dim3((NN + 255) / 256), dim3(256), 0, stream>>>(counts);
  prep_w_kernel<<<dim3((WT_TOTAL + 255) / 256), dim3(256), 0, stream>>>(
      Wang_v, W1v, Wlin_v, W2v, Wang_k, W1k, Wlin_k, W2k, Wout, Wq, Wdot, wt);
  qw_kernel<<<dim3((NN + 63) / 64), dim3(256), 0, stream>>>(node_attr, wt, qw);
  count_kernel<<<dim3((NE + 255) / 256), dim3(256), 0, stream>>>(edge_index, counts, edge_rel);
  scan_kernel<<<dim3(1), dim3(1024), 0, stream>>>(counts, row_ptr);
  conv_fused_kernel<<<dim3(NE / 64), dim3(256), 0, stream>>>(
      node_attr, edge_attr, edge_sh, edge_index, b1v, b1k, wt, qw, row_ptr, edge_rel, v_e, alpha);
  out_kernel<<<dim3(3125), dim3(256), 0, stream>>>(row_ptr, alpha, v_e, wt, out);
}

// Round 13
// 572.095 us; speedup vs baseline: 1.1206x; 1.0034x over previous
//
#include <hip/hip_runtime.h>
#include <stdint.h>

#define NN 50000
#define NE 800000
#define STRIP 49   // ceil(NN/1024)

typedef unsigned int u32;
typedef uint16_t u16;

__device__ __forceinline__ float b2f(u16 u){ return __builtin_bit_cast(float, (u32)((u32)u << 16)); }
__device__ __forceinline__ float b2f_lo(u32 p){ return __builtin_bit_cast(float, p << 16); }
__device__ __forceinline__ float b2f_hi(u32 p){ return __builtin_bit_cast(float, p & 0xffff0000u); }
__device__ __forceinline__ u32 f2b_bits(float f){ u32 u = __builtin_bit_cast(u32, f); return (u + 0x7fffu + ((u >> 16) & 1u)) >> 16; }
__device__ __forceinline__ u16 f2b(float f){ return (u16)f2b_bits(f); }
// RNE pack of 2 f32 -> bf16x2 in one instruction (same rounding as emulation)
__device__ __forceinline__ u32 packb(float lo, float hi){
  u32 r;
  asm("v_cvt_pk_bf16_f32 %0, %1, %2" : "=v"(r) : "v"(lo), "v"(hi));
  return r;
}

typedef __bf16 bf16x2 __attribute__((ext_vector_type(2)));
#if defined(__has_builtin)
#if __has_builtin(__builtin_amdgcn_fdot2_f32_bf16)
#define HAVE_DOT2_BUILTIN 1
#endif
#endif

#ifdef HAVE_DOT2_BUILTIN
__device__ __forceinline__ float dot2b(u32 a, u32 b, float c){
  return __builtin_amdgcn_fdot2_f32_bf16(__builtin_bit_cast(bf16x2, a),
                                         __builtin_bit_cast(bf16x2, b), c, false);
}
#else
__device__ __forceinline__ float dot2b(u32 a, u32 b, float c){
  c = fmaf(b2f_lo(a), b2f_lo(b), c);
  return fmaf(b2f_hi(a), b2f_hi(b), c);
}
#endif

// ---- MFMA plumbing ----
typedef __attribute__((ext_vector_type(8))) short short8;
typedef __attribute__((ext_vector_type(4))) float f32x4;
__device__ __forceinline__ f32x4 mf32(uint4 a, uint4 b, f32x4 c){
  return __builtin_amdgcn_mfma_f32_16x16x32_bf16(
      __builtin_bit_cast(short8, a), __builtin_bit_cast(short8, b), c, 0, 0, 0);
}

// channel permutation for 128-row weight blocks consumed as A-operands in two
// 16-row fragments/wave: stored row n -> actual channel. Makes each thread own
// 8 CONSECUTIVE channels (32*wv + 8*lq .. +7) across its two fragments.
__device__ __forceinline__ int chperm(int n){
  return 32 * ((n & 63) >> 4) + 8 * ((n & 15) >> 2) + 4 * (n >> 6) + (n & 3);
}

// pre-transposed weight layout offsets in u16 units (padded, zero-filled)
// Wang_* hold data at k in [16,32) (SH upper half of fused [EA|SH] operand).
// WANG_V/WANG_K/WLIN_V/W2_V rows are chperm-permuted.
#define OFF_WANG_V 0        // [128][40]
#define OFF_W1_V   5120     // [64][40]
#define OFF_WLIN_V 7680     // [128][136]
#define OFF_W2_V   25088    // [128][72]
#define OFF_WANG_K 34304    // [128][40]
#define OFF_W1_K   39424    // [64][40]
#define OFF_WLIN_K 41984    // [64][136]
#define OFF_W2_K   50688    // [64][72]
#define OFF_WOUT   55296    // [128][136]
#define OFF_WQD    72704    // [64][136]  (Wq @ blockdiag(Wdot))^T
#define WT_TOTAL   81408

__global__ __launch_bounds__(256) void zero_kernel(int* __restrict__ counts)
{
  int i = blockIdx.x * 256 + threadIdx.x;
  if (i < NN) counts[i] = 0;
}

// ---------------- one-time weight transpose/pad/bf16 prep
__global__ __launch_bounds__(256) void prep_w_kernel(
    const float* __restrict__ Wang_v, const float* __restrict__ W1_v,
    const float* __restrict__ Wlin_v, const float* __restrict__ W2_v,
    const float* __restrict__ Wang_k, const float* __restrict__ W1_k,
    const float* __restrict__ Wlin_k, const float* __restrict__ W2_k,
    const float* __restrict__ Wout, const float* __restrict__ Wq,
    const float* __restrict__ Wdot,
    u16* __restrict__ wt)
{
  int idx = blockIdx.x * 256 + threadIdx.x;
  if (idx >= WT_TOTAL) return;
  float val = 0.f;
  if (idx < OFF_W1_V) {
    int l = idx - OFF_WANG_V, n = l / 40, k = l % 40;
    if (k >= 16 && k < 32) val = Wang_v[chperm(n) * 16 + (k - 16)];
  } else if (idx < OFF_WLIN_V) {
    int l = idx - OFF_W1_V, n = l / 40, k = l % 40;
    if (k < 16) val = W1_v[k * 64 + n];
  } else if (idx < OFF_W2_V) {
    int l = idx - OFF_WLIN_V, n = l / 136, k = l % 136;
    if (k < 128) val = Wlin_v[k * 128 + chperm(n)];
  } else if (idx < OFF_WANG_K) {
    int l = idx - OFF_W2_V, n = l / 72, k = l % 72;
    if (k < 64) val = W2_v[k * 128 + chperm(n)];
  } else if (idx < OFF_W1_K) {
    int l = idx - OFF_WANG_K, n = l / 40, k = l % 40;
    if (k >= 16 && k < 32) val = Wang_k[chperm(n) * 16 + (k - 16)];
  } else if (idx < OFF_WLIN_K) {
    int l = idx - OFF_W1_K, n = l / 40, k = l % 40;
    if (k < 16) val = W1_k[k * 64 + n];
  } else if (idx < OFF_W2_K) {
    int l = idx - OFF_WLIN_K, n = l / 136, k = l % 136;
    if (k < 128) val = Wlin_k[k * 64 + n];
  } else if (idx < OFF_WOUT) {
    int l = idx - OFF_W2_K, n = l / 72, k = l % 72;
    if (k < 64) val = W2_k[k * 64 + n];
  } else if (idx < OFF_WQD) {                // WoutT: B^T[n][k] = Wout[k*128+n]
    int l = idx - OFF_WOUT, n = l / 136, k = l % 136;
    if (k < 128) val = Wout[k * 128 + n];
  } else {                                   // WqdT[n][k] = sum_i Wq[k,h*8+i]*Wdot[i,r]
    int l = idx - OFF_WQD, n = l / 136, k = l % 136;
    if (k < 128) {
      int h = n >> 3, r = n & 7;
      float s = 0.f;
#pragma unroll
      for (int i = 0; i < 8; ++i) s += Wq[k * 64 + h * 8 + i] * Wdot[i * 8 + r];
      val = s;
    }
  }
  wt[idx] = f2b(val);
}

// ---------------- qw = node_attr @ Wqd, MFMA, 64 nodes/block
__global__ __launch_bounds__(256) void qw_kernel(const float* __restrict__ node_attr,
                                                 const u16* __restrict__ wt,
                                                 u16* __restrict__ qw)
{
  __shared__ __align__(16) u16 sX[64 * 136];
  uint4* sX4 = (uint4*)sX;
  u32* sX32 = (u32*)sX;
  const uint4* wt4 = (const uint4*)wt;
  const int tid = threadIdx.x, wv = tid >> 6, lane = tid & 63, lq = lane >> 4, ln = lane & 15;
  const int n0 = blockIdx.x * 64;
  uint4 rB[4];
#pragma unroll
  for (int ks = 0; ks < 4; ++ks) rB[ks] = wt4[9088 + (wv * 16 + ln) * 17 + ks * 4 + lq];
  {
    int row = tid >> 2, q4 = tid & 3;
    int n = n0 + row;
    bool valid = n < NN;
    const float4* xp = (const float4*)(node_attr + (size_t)(valid ? n : 0) * 128);
#pragma unroll
    for (int i = 0; i < 8; ++i) {
      float4 v = valid ? xp[q4 * 8 + i] : make_float4(0.f, 0.f, 0.f, 0.f);
      sX32[row * 68 + (q4 * 8 + i) * 2]     = packb(v.x, v.y);
      sX32[row * 68 + (q4 * 8 + i) * 2 + 1] = packb(v.z, v.w);
    }
  }
  __syncthreads();
  const f32x4 z4 = {0.f, 0.f, 0.f, 0.f};
  int col = wv * 16 + ln;
#pragma unroll
  for (int et = 0; et < 4; ++et) {
    f32x4 acc = z4;
#pragma unroll
    for (int ks = 0; ks < 4; ++ks) acc = mf32(sX4[(et * 16 + ln) * 17 + ks * 4 + lq], rB[ks], acc);
#pragma unroll
    for (int r = 0; r < 4; ++r) {
      int rr = n0 + et * 16 + lq * 4 + r;
      if (rr < NN) qw[(size_t)rr * 64 + col] = f2b(acc[r]);
    }
  }
}

// ---------------- CSR build. count_kernel also records each edge's
// within-segment rank (the atomic's return value) so edge_pos[e] =
// row_ptr[dst] + edge_rel[e] is later PURE ARITHMETIC (fill_kernel deleted).
__global__ __launch_bounds__(256) void count_kernel(const int* __restrict__ edge_index,
                                                    int* __restrict__ counts,
                                                    int* __restrict__ edge_rel)
{
  int e = blockIdx.x * 256 + threadIdx.x;
  if (e < NE) {
    int d = edge_index[NE + e]; if ((u32)d >= NN) d = 0;
    edge_rel[e] = atomicAdd(&counts[d], 1);
  }
}

__global__ __launch_bounds__(1024) void scan_kernel(const int* __restrict__ counts,
                                                    int* __restrict__ row_ptr)
{
  __shared__ int s[1024];
  int tid = threadIdx.x;
  int base = tid * STRIP;
  int sum = 0;
  for (int i = 0; i < STRIP; ++i) { int idx = base + i; sum += (idx < NN) ? counts[idx] : 0; }
  s[tid] = sum;
  __syncthreads();
  for (int off = 1; off < 1024; off <<= 1) {
    int v = s[tid];
    int add = (tid >= off) ? s[tid - off] : 0;
    __syncthreads();
    s[tid] = v + add;
    __syncthreads();
  }
  int running = (tid == 0) ? 0 : s[tid - 1];
  for (int i = 0; i < STRIP; ++i) {
    int idx = base + i;
    if (idx < NN) { row_ptr[idx] = running; running += counts[idx]; }
  }
  if (tid == 1023) row_ptr[NN] = running;
}

// ---------------- fused MFMA conv (single pass, swapped operands) + alpha.
// alpha is stored as exp(q.k): softmax is shift-invariant and |q.k| is O(10)
// for this model, so no max subtraction is needed; out_kernel's inner loop
// becomes pure FMA. v/alpha scatter-written at row_ptr[dst] + edge_rel[e].
__global__ __launch_bounds__(256, 2) void conv_fused_kernel(
    const float* __restrict__ node_attr, const float* __restrict__ edge_attr,
    const float* __restrict__ edge_sh, const int* __restrict__ edge_index,
    const float* __restrict__ b1v, const float* __restrict__ b1k,
    const u16* __restrict__ wt, const u16* __restrict__ qw,
    const int* __restrict__ row_ptr, const int* __restrict__ edge_rel,
    u16* __restrict__ v_out, float* __restrict__ alpha)
{
  __shared__ __align__(16) u16 sC[64 * 40];    // fused [EA(16)|SH(16)|pad(8)]
  __shared__ __align__(16) u16 sX[64 * 136];   // t_v -> v result
  __shared__ __align__(16) u16 sTk[64 * 136];  // t_k
  __shared__ __align__(16) u16 sHv[64 * 72];   // relu(EA@W1v+b)
  __shared__ __align__(16) u16 sHk[64 * 72];   // relu(EA@W1k+b) -> k result
  uint4* sC4 = (uint4*)sC; u32* sC32 = (u32*)sC;
  uint4* sX4 = (uint4*)sX;
  uint4* sTk4 = (uint4*)sTk;
  uint4* sHv4 = (uint4*)sHv;
  uint4* sHk4 = (uint4*)sHk;
  const uint4* wt4 = (const uint4*)wt;

  const int tid = threadIdx.x;
  const int wv = tid >> 6, lane = tid & 63, lq = lane >> 4, ln = lane & 15;
  const int e0 = blockIdx.x * 64;
  const int nA = wv * 16 + ln, nB = (wv + 4) * 16 + ln;
  const int cb  = wv * 16 + 4 * lq;   // H-channel base (natural rows)
  const int cb8 = wv * 32 + 8 * lq;   // T-channel base (chperm rows)

  // dst q gather + CSR position (arithmetic from row_ptr + rel) early
  const int el = tid >> 2, p = tid & 3;
  int dq = edge_index[NE + e0 + el]; if ((u32)dq >= NN) dq = 0;
  const uint4* qptr = (const uint4*)(qw + (size_t)dq * 64 + p * 16);
  uint4 q0 = qptr[0], q1 = qptr[1];
  int pos_el = row_ptr[dq] + edge_rel[e0 + el];
  if ((u32)pos_el >= NE) pos_el = 0;

  // src indices for the 4 edges this thread computes in phase A
  int srcs[4];
#pragma unroll
  for (int et = 0; et < 4; ++et) {
    int s = edge_index[e0 + et * 16 + ln];
    if ((u32)s >= NN) s = 0;
    srcs[et] = s;
  }

  // phase-A weight fragments
  uint4 rW1V    = wt4[640 + nA * 5 + lq];
  uint4 rW1K    = wt4[4928 + nA * 5 + lq];
  uint4 rWangV0 = wt4[nA * 5 + lq],        rWangV1 = wt4[nB * 5 + lq];
  uint4 rWangK0 = wt4[4288 + nA * 5 + lq], rWangK1 = wt4[4288 + nB * 5 + lq];
  float4 bV = *(const float4*)(b1v + cb);
  float4 bK = *(const float4*)(b1k + cb);

  // stage fused EA|SH operand
  {
    int r = tid >> 2, kq = tid & 3;
    float4 ea = ((const float4*)(edge_attr + (size_t)(e0 + r) * 16))[kq];
    *(uint2*)(sC32 + r * 20 + kq * 2) = make_uint2(packb(ea.x, ea.y), packb(ea.z, ea.w));
    float4 sh = ((const float4*)(edge_sh + (size_t)(e0 + r) * 16))[kq];
    *(uint2*)(sC32 + r * 20 + 8 + kq * 2) = make_uint2(packb(sh.x, sh.y), packb(sh.z, sh.w));
  }
  // x prefetch for et=0 (channels cb8..cb8+7, f32, straight to regs)
  const float* xp0 = node_attr + (size_t)srcs[0] * 128 + cb8;
  float4 xa = *(const float4*)xp0;
  float4 xb = *(const float4*)(xp0 + 4);
  __syncthreads();   // S1

  const f32x4 z4 = {0.f, 0.f, 0.f, 0.f};
  // ---- phase A: radial MLP hidden + depthwise SH products
#pragma unroll
  for (int et = 0; et < 4; ++et) {
    float4 xa_n, xb_n;
    if (et < 3) {
      const float* xp = node_attr + (size_t)srcs[et + 1] * 128 + cb8;
      xa_n = *(const float4*)xp;
      xb_n = *(const float4*)(xp + 4);
    }
    uint4 aC = sC4[(et * 16 + ln) * 5 + lq];
    f32x4 hv  = mf32(rW1V, aC, z4);
    f32x4 hk  = mf32(rW1K, aC, z4);
    f32x4 t0v = mf32(rWangV0, aC, z4);
    f32x4 t1v = mf32(rWangV1, aC, z4);
    f32x4 t0k = mf32(rWangK0, aC, z4);
    f32x4 t1k = mf32(rWangK1, aC, z4);
    const int edge = et * 16 + ln;
    sX4[edge * 17 + 4 * wv + lq] = make_uint4(
        packb(t0v[0] * xa.x, t0v[1] * xa.y), packb(t0v[2] * xa.z, t0v[3] * xa.w),
        packb(t1v[0] * xb.x, t1v[1] * xb.y), packb(t1v[2] * xb.z, t1v[3] * xb.w));
    sTk4[edge * 17 + 4 * wv + lq] = make_uint4(
        packb(t0k[0] * xa.x, t0k[1] * xa.y), packb(t0k[2] * xa.z, t0k[3] * xa.w),
        packb(t1k[0] * xb.x, t1k[1] * xb.y), packb(t1k[2] * xb.z, t1k[3] * xb.w));
    *(uint2*)(sHv + edge * 72 + cb) = make_uint2(
        packb(fmaxf(hv[0] + bV.x, 0.f), fmaxf(hv[1] + bV.y, 0.f)),
        packb(fmaxf(hv[2] + bV.z, 0.f), fmaxf(hv[3] + bV.w, 0.f)));
    *(uint2*)(sHk + edge * 72 + cb) = make_uint2(
        packb(fmaxf(hk[0] + bK.x, 0.f), fmaxf(hk[1] + bK.y, 0.f)),
        packb(fmaxf(hk[2] + bK.z, 0.f), fmaxf(hk[3] + bK.w, 0.f)));
    xa = xa_n; xb = xb_n;
  }

  // phase-B weight fragments (issued here; in flight across the barrier)
  uint4 rWlinV[2][4], rWlinK[4], rW2V[2][2], rW2K[2];
#pragma unroll
  for (int ks = 0; ks < 4; ++ks) {
    rWlinV[0][ks] = wt4[960 + nA * 17 + ks * 4 + lq];
    rWlinV[1][ks] = wt4[960 + nB * 17 + ks * 4 + lq];
    rWlinK[ks]    = wt4[5248 + nA * 17 + ks * 4 + lq];
  }
#pragma unroll
  for (int ks = 0; ks < 2; ++ks) {
    rW2V[0][ks] = wt4[3136 + nA * 9 + ks * 4 + lq];
    rW2V[1][ks] = wt4[3136 + nB * 9 + ks * 4 + lq];
    rW2K[ks]    = wt4[6336 + nA * 9 + ks * 4 + lq];
  }
  __syncthreads();  // S2

  // ---- phase B: channel-mix (Wlin) and radial out (W2); results packed in regs
  uint4 pv[4]; uint2 pk[4];
#pragma unroll
  for (int et = 0; et < 4; ++et) {
    const int er = et * 16 + ln;
    f32x4 acc0 = z4, acc1 = z4, acck = z4;
#pragma unroll
    for (int ks = 0; ks < 4; ++ks) {
      uint4 tb = sX4[er * 17 + ks * 4 + lq];
      acc0 = mf32(rWlinV[0][ks], tb, acc0);
      acc1 = mf32(rWlinV[1][ks], tb, acc1);
      acck = mf32(rWlinK[ks], sTk4[er * 17 + ks * 4 + lq], acck);
    }
    f32x4 b0 = z4, b1 = z4, bk = z4;
#pragma unroll
    for (int ks = 0; ks < 2; ++ks) {
      uint4 hb = sHv4[er * 9 + ks * 4 + lq];
      b0 = mf32(rW2V[0][ks], hb, b0);
      b1 = mf32(rW2V[1][ks], hb, b1);
      bk = mf32(rW2K[ks], sHk4[er * 9 + ks * 4 + lq], bk);
    }
    pv[et] = make_uint4(packb(acc0[0] * b0[0], acc0[1] * b0[1]),
                        packb(acc0[2] * b0[2], acc0[3] * b0[3]),
                        packb(acc1[0] * b1[0], acc1[1] * b1[1]),
                        packb(acc1[2] * b1[2], acc1[3] * b1[3]));
    pk[et] = make_uint2(packb(acck[0] * bk[0], acck[1] * bk[1]),
                        packb(acck[2] * bk[2], acck[3] * bk[3]));
  }
  __syncthreads();  // S3

  // ---- result staging: v as b128 (channels cb8..cb8+7), k as b64
#pragma unroll
  for (int et = 0; et < 4; ++et) {
    const int edge = et * 16 + ln;
    sX4[edge * 17 + 4 * wv + lq] = pv[et];
    *(uint2*)(sHk + edge * 72 + cb) = pk[et];
  }
  __syncthreads();  // S4

  // v store, scattered to CSR slot (256B contiguous per edge; row==el)
  {
    int row = tid >> 2, seg = tid & 3;
    uint4* gp = (uint4*)(v_out + (size_t)pos_el * 128);
#pragma unroll
    for (int i = 0; i < 4; ++i) gp[seg * 4 + i] = sX4[row * 17 + seg * 4 + i];
  }
  // alpha = exp(q . k)  (bf16 dot2 + expf), scattered to CSR slot
  {
    uint4 k0 = sHk4[el * 9 + p * 2];
    uint4 k1 = sHk4[el * 9 + p * 2 + 1];
    float a0 = 0.f, a1 = 0.f;
    a0 = dot2b(q0.x, k0.x, a0); a0 = dot2b(q0.y, k0.y, a0);
    a0 = dot2b(q0.z, k0.z, a0); a0 = dot2b(q0.w, k0.w, a0);
    a1 = dot2b(q1.x, k1.x, a1); a1 = dot2b(q1.y, k1.y, a1);
    a1 = dot2b(q1.z, k1.z, a1); a1 = dot2b(q1.w, k1.w, a1);
    ((float2*)(alpha + (size_t)pos_el * 8))[p] = make_float2(__expf(a0), __expf(a1));
  }
}

// ---------------- per-node weighted sum over SEQUENTIAL CSR-ordered
// exp(alpha)/v streams — pure FMA inner loop (no exp, no max; alpha already
// exponentiated in conv), 2-way split accumulators + MFMA @Wout epilogue.
__global__ __launch_bounds__(256) void out_kernel(
    const int* __restrict__ row_ptr,
    const float* __restrict__ alpha, const u16* __restrict__ v_e,
    const u16* __restrict__ wt, float* __restrict__ out)
{
  __shared__ __align__(16) u16 sAgg[16 * 136];
  u32* sAgg32 = (u32*)sAgg;
  uint4* sAgg4 = (uint4*)sAgg;
  const uint4* wt4 = (const uint4*)wt;
  const u32* v32 = (const u32*)v_e;
  const int tid = threadIdx.x, wv = tid >> 6, lane = tid & 63, lq = lane >> 4, ln = lane & 15;
  const f32x4 z4 = {0.f, 0.f, 0.f, 0.f};
  uint4 rWT[2][4];
#pragma unroll
  for (int c = 0; c < 2; ++c) {
    int n = (wv * 2 + c) * 16 + ln;
#pragma unroll
    for (int ks = 0; ks < 4; ++ks) rWT[c][ks] = wt4[6912 + n * 17 + ks * 4 + lq];
  }
  const int hh = lane >> 3;   // head of cols {2*lane, 2*lane+1}
  const int grp = blockIdx.x;
#pragma unroll 1
  for (int i = 0; i < 4; ++i) {
    int n = grp * 16 + wv * 4 + i;
    int beg = row_ptr[n], end = row_ptr[n + 1];
    if (beg < 0) beg = 0; if (beg > NE) beg = NE;
    if (end < beg) end = beg; if (end > NE) end = NE;
    int deg = end - beg;
    float l0 = 0.f, a0A = 0.f, a0B = 0.f;
    float l1 = 0.f, a1A = 0.f, a1B = 0.f;
    int j = 0;
#pragma unroll 1
    for (; j + 4 <= deg; j += 4) {
      size_t b = (size_t)(beg + j);
      float w0 = alpha[(b)     * 8 + hh]; u32 x0 = v32[(b)     * 64 + lane];
      float w1 = alpha[(b + 1) * 8 + hh]; u32 x1 = v32[(b + 1) * 64 + lane];
      float w2 = alpha[(b + 2) * 8 + hh]; u32 x2 = v32[(b + 2) * 64 + lane];
      float w3 = alpha[(b + 3) * 8 + hh]; u32 x3 = v32[(b + 3) * 64 + lane];
      l0 += w0; a0A = fmaf(w0, b2f_lo(x0), a0A); a0B = fmaf(w0, b2f_hi(x0), a0B);
      l1 += w1; a1A = fmaf(w1, b2f_lo(x1), a1A); a1B = fmaf(w1, b2f_hi(x1), a1B);
      l0 += w2; a0A = fmaf(w2, b2f_lo(x2), a0A); a0B = fmaf(w2, b2f_hi(x2), a0B);
      l1 += w3; a1A = fmaf(w3, b2f_lo(x3), a1A); a1B = fmaf(w3, b2f_hi(x3), a1B);
    }
#pragma unroll 1
    for (; j < deg; ++j) {
      size_t b = (size_t)(beg + j);
      float w = alpha[b * 8 + hh]; u32 x = v32[b * 64 + lane];
      l0 += w; a0A = fmaf(w, b2f_lo(x), a0A); a0B = fmaf(w, b2f_hi(x), a0B);
    }
    float l = l0 + l1;
    float accA = a0A + a1A;
    float accB = a0B + a1B;
    float inv = (l > 0.f) ? (1.f / l) : 0.f;
    accA *= inv; accB *= inv;
    sAgg32[(wv * 4 + i) * 68 + lane] = packb(accA, accB);
  }
  __syncthreads();
#pragma unroll
  for (int c = 0; c < 2; ++c) {
    f32x4 acc = z4;
#pragma unroll
    for (int ks = 0; ks < 4; ++ks) acc = mf32(sAgg4[ln * 17 + ks * 4 + lq], rWT[c][ks], acc);
    int col = (wv * 2 + c) * 16 + ln;
#pragma unroll
    for (int r = 0; r < 4; ++r)
      out[(size_t)(grp * 16 + lq * 4 + r) * 128 + col] = acc[r];
  }
}

extern "C" void kernel_launch(void* const* d_in, const int* in_sizes, int n_in,
                              void* d_out, int out_size, void* d_ws, size_t ws_size,
                              hipStream_t stream)
{
  const float* node_attr = (const float*)d_in[0];
  const float* edge_attr = (const float*)d_in[1];
  const float* edge_sh   = (const float*)d_in[2];
  const float* Wq        = (const float*)d_in[3];
  const float* Wang_k    = (const float*)d_in[4];
  const float* Wlin_k    = (const float*)d_in[5];
  const float* W1k       = (const float*)d_in[6];
  const float* b1k       = (const float*)d_in[7];
  const float* W2k       = (const float*)d_in[8];
  const float* Wang_v    = (const float*)d_in[9];
  const float* Wlin_v    = (const float*)d_in[10];
  const float* W1v       = (const float*)d_in[11];
  const float* b1v       = (const float*)d_in[12];
  const float* W2v       = (const float*)d_in[13];
  const float* Wdot      = (const float*)d_in[14];
  const float* Wout      = (const float*)d_in[15];
  const int* edge_index  = (const int*)d_in[16];
  float* out = (float*)d_out;

  char* ws = (char*)d_ws;
  u16*   v_e      = (u16*)(ws + 0);                 // E*128*2  = 204,800,000 (CSR order)
  float* alpha    = (float*)(ws + 204800000);       // E*8*4    =  25,600,000 (CSR order, exp'd)
  u16*   qw       = (u16*)(ws + 230400000);         // N*64*2   =   6,400,000
  int*   counts   = (int*)(ws + 236800000);         // 200,064
  int*   row_ptr  = (int*)(ws + 237000064);         // 200,064
  int*   edge_rel = (int*)(ws + 237400192);         // 3,200,000 (within-segment rank)
  u16*   wt       = (u16*)(ws + 240600192);         // 162,816 -> total 240,763,008

  zero_kernel<<<dim3((NN + 255) / 256), dim3(256), 0, stream>>>(counts);
  prep_w_kernel<<<dim3((WT_TOTAL + 255) / 256), dim3(256), 0, stream>>>(
      Wang_v, W1v, Wlin_v, W2v, Wang_k, W1k, Wlin_k, W2k, Wout, Wq, Wdot, wt);
  qw_kernel<<<dim3((NN + 63) / 64), dim3(256), 0, stream>>>(node_attr, wt, qw);
  count_kernel<<<dim3((NE + 255) / 256), dim3(256), 0, stream>>>(edge_index, counts, edge_rel);
  scan_kernel<<<dim3(1), dim3(1024), 0, stream>>>(counts, row_ptr);
  conv_fused_kernel<<<dim3(NE / 64), dim3(256), 0, stream>>>(
      node_attr, edge_attr, edge_sh, edge_index, b1v, b1k, wt, qw, row_ptr, edge_rel, v_e, alpha);
  out_kernel<<<dim3(3125), dim3(256), 0, stream>>>(row_ptr, alpha, v_e, wt, out);
}

// Round 14
// 569.940 us; speedup vs baseline: 1.1249x; 1.0038x over previous
//
#include <hip/hip_runtime.h>
#include <stdint.h>

#define NN 50000
#define NE 800000
#define STRIP 49   // ceil(NN/1024)

typedef unsigned int u32;
typedef uint16_t u16;

__device__ __forceinline__ float b2f(u16 u){ return __builtin_bit_cast(float, (u32)((u32)u << 16)); }
__device__ __forceinline__ float b2f_lo(u32 p){ return __builtin_bit_cast(float, p << 16); }
__device__ __forceinline__ float b2f_hi(u32 p){ return __builtin_bit_cast(float, p & 0xffff0000u); }
__device__ __forceinline__ u32 f2b_bits(float f){ u32 u = __builtin_bit_cast(u32, f); return (u + 0x7fffu + ((u >> 16) & 1u)) >> 16; }
__device__ __forceinline__ u16 f2b(float f){ return (u16)f2b_bits(f); }
// RNE pack of 2 f32 -> bf16x2 in one instruction (same rounding as emulation)
__device__ __forceinline__ u32 packb(float lo, float hi){
  u32 r;
  asm("v_cvt_pk_bf16_f32 %0, %1, %2" : "=v"(r) : "v"(lo), "v"(hi));
  return r;
}

typedef __bf16 bf16x2 __attribute__((ext_vector_type(2)));
#if defined(__has_builtin)
#if __has_builtin(__builtin_amdgcn_fdot2_f32_bf16)
#define HAVE_DOT2_BUILTIN 1
#endif
#endif

#ifdef HAVE_DOT2_BUILTIN
__device__ __forceinline__ float dot2b(u32 a, u32 b, float c){
  return __builtin_amdgcn_fdot2_f32_bf16(__builtin_bit_cast(bf16x2, a),
                                         __builtin_bit_cast(bf16x2, b), c, false);
}
#else
__device__ __forceinline__ float dot2b(u32 a, u32 b, float c){
  c = fmaf(b2f_lo(a), b2f_lo(b), c);
  return fmaf(b2f_hi(a), b2f_hi(b), c);
}
#endif

// ---- MFMA plumbing ----
typedef __attribute__((ext_vector_type(8))) short short8;
typedef __attribute__((ext_vector_type(4))) float f32x4;
__device__ __forceinline__ f32x4 mf32(uint4 a, uint4 b, f32x4 c){
  return __builtin_amdgcn_mfma_f32_16x16x32_bf16(
      __builtin_bit_cast(short8, a), __builtin_bit_cast(short8, b), c, 0, 0, 0);
}

// channel permutation for 128-row weight blocks consumed as A-operands in two
// 16-row fragments/wave: stored row n -> actual channel. Makes each thread own
// 8 CONSECUTIVE channels (32*wv + 8*lq .. +7) across its two fragments.
__device__ __forceinline__ int chperm(int n){
  return 32 * ((n & 63) >> 4) + 8 * ((n & 15) >> 2) + 4 * (n >> 6) + (n & 3);
}

// pre-transposed weight layout offsets in u16 units (padded, zero-filled)
// Wang_* hold data at k in [16,32) (SH upper half of fused [EA|SH] operand).
// WANG_V/WANG_K/WLIN_V/W2_V rows are chperm-permuted.
#define OFF_WANG_V 0        // [128][40]
#define OFF_W1_V   5120     // [64][40]
#define OFF_WLIN_V 7680     // [128][136]
#define OFF_W2_V   25088    // [128][72]
#define OFF_WANG_K 34304    // [128][40]
#define OFF_W1_K   39424    // [64][40]
#define OFF_WLIN_K 41984    // [64][136]
#define OFF_W2_K   50688    // [64][72]
#define OFF_WOUT   55296    // [128][136]
#define OFF_WQD    72704    // [64][136]  (Wq @ blockdiag(Wdot))^T
#define WT_TOTAL   81408

__global__ __launch_bounds__(256) void zero_kernel(int* __restrict__ counts)
{
  int i = blockIdx.x * 256 + threadIdx.x;
  if (i < NN) counts[i] = 0;
}

// ---------------- one-time weight transpose/pad/bf16 prep
__global__ __launch_bounds__(256) void prep_w_kernel(
    const float* __restrict__ Wang_v, const float* __restrict__ W1_v,
    const float* __restrict__ Wlin_v, const float* __restrict__ W2_v,
    const float* __restrict__ Wang_k, const float* __restrict__ W1_k,
    const float* __restrict__ Wlin_k, const float* __restrict__ W2_k,
    const float* __restrict__ Wout, const float* __restrict__ Wq,
    const float* __restrict__ Wdot,
    u16* __restrict__ wt)
{
  int idx = blockIdx.x * 256 + threadIdx.x;
  if (idx >= WT_TOTAL) return;
  float val = 0.f;
  if (idx < OFF_W1_V) {
    int l = idx - OFF_WANG_V, n = l / 40, k = l % 40;
    if (k >= 16 && k < 32) val = Wang_v[chperm(n) * 16 + (k - 16)];
  } else if (idx < OFF_WLIN_V) {
    int l = idx - OFF_W1_V, n = l / 40, k = l % 40;
    if (k < 16) val = W1_v[k * 64 + n];
  } else if (idx < OFF_W2_V) {
    int l = idx - OFF_WLIN_V, n = l / 136, k = l % 136;
    if (k < 128) val = Wlin_v[k * 128 + chperm(n)];
  } else if (idx < OFF_WANG_K) {
    int l = idx - OFF_W2_V, n = l / 72, k = l % 72;
    if (k < 64) val = W2_v[k * 128 + chperm(n)];
  } else if (idx < OFF_W1_K) {
    int l = idx - OFF_WANG_K, n = l / 40, k = l % 40;
    if (k >= 16 && k < 32) val = Wang_k[chperm(n) * 16 + (k - 16)];
  } else if (idx < OFF_WLIN_K) {
    int l = idx - OFF_W1_K, n = l / 40, k = l % 40;
    if (k < 16) val = W1_k[k * 64 + n];
  } else if (idx < OFF_W2_K) {
    int l = idx - OFF_WLIN_K, n = l / 136, k = l % 136;
    if (k < 128) val = Wlin_k[k * 64 + n];
  } else if (idx < OFF_WOUT) {
    int l = idx - OFF_W2_K, n = l / 72, k = l % 72;
    if (k < 64) val = W2_k[k * 64 + n];
  } else if (idx < OFF_WQD) {                // WoutT: B^T[n][k] = Wout[k*128+n]
    int l = idx - OFF_WOUT, n = l / 136, k = l % 136;
    if (k < 128) val = Wout[k * 128 + n];
  } else {                                   // WqdT[n][k] = sum_i Wq[k,h*8+i]*Wdot[i,r]
    int l = idx - OFF_WQD, n = l / 136, k = l % 136;
    if (k < 128) {
      int h = n >> 3, r = n & 7;
      float s = 0.f;
#pragma unroll
      for (int i = 0; i < 8; ++i) s += Wq[k * 64 + h * 8 + i] * Wdot[i * 8 + r];
      val = s;
    }
  }
  wt[idx] = f2b(val);
}

// ---------------- qw = node_attr @ Wqd, MFMA, 64 nodes/block
__global__ __launch_bounds__(256) void qw_kernel(const float* __restrict__ node_attr,
                                                 const u16* __restrict__ wt,
                                                 u16* __restrict__ qw)
{
  __shared__ __align__(16) u16 sX[64 * 136];
  uint4* sX4 = (uint4*)sX;
  u32* sX32 = (u32*)sX;
  const uint4* wt4 = (const uint4*)wt;
  const int tid = threadIdx.x, wv = tid >> 6, lane = tid & 63, lq = lane >> 4, ln = lane & 15;
  const int n0 = blockIdx.x * 64;
  uint4 rB[4];
#pragma unroll
  for (int ks = 0; ks < 4; ++ks) rB[ks] = wt4[9088 + (wv * 16 + ln) * 17 + ks * 4 + lq];
  {
    int row = tid >> 2, q4 = tid & 3;
    int n = n0 + row;
    bool valid = n < NN;
    const float4* xp = (const float4*)(node_attr + (size_t)(valid ? n : 0) * 128);
#pragma unroll
    for (int i = 0; i < 8; ++i) {
      float4 v = valid ? xp[q4 * 8 + i] : make_float4(0.f, 0.f, 0.f, 0.f);
      sX32[row * 68 + (q4 * 8 + i) * 2]     = packb(v.x, v.y);
      sX32[row * 68 + (q4 * 8 + i) * 2 + 1] = packb(v.z, v.w);
    }
  }
  __syncthreads();
  const f32x4 z4 = {0.f, 0.f, 0.f, 0.f};
  int col = wv * 16 + ln;
#pragma unroll
  for (int et = 0; et < 4; ++et) {
    f32x4 acc = z4;
#pragma unroll
    for (int ks = 0; ks < 4; ++ks) acc = mf32(sX4[(et * 16 + ln) * 17 + ks * 4 + lq], rB[ks], acc);
#pragma unroll
    for (int r = 0; r < 4; ++r) {
      int rr = n0 + et * 16 + lq * 4 + r;
      if (rr < NN) qw[(size_t)rr * 64 + col] = f2b(acc[r]);
    }
  }
}

// ---------------- CSR build. count_kernel also records each edge's
// within-segment rank (the atomic's return value) so edge_pos[e] =
// row_ptr[dst] + edge_rel[e] is later PURE ARITHMETIC (fill_kernel deleted).
__global__ __launch_bounds__(256) void count_kernel(const int* __restrict__ edge_index,
                                                    int* __restrict__ counts,
                                                    int* __restrict__ edge_rel)
{
  int e = blockIdx.x * 256 + threadIdx.x;
  if (e < NE) {
    int d = edge_index[NE + e]; if ((u32)d >= NN) d = 0;
    edge_rel[e] = atomicAdd(&counts[d], 1);
  }
}

__global__ __launch_bounds__(1024) void scan_kernel(const int* __restrict__ counts,
                                                    int* __restrict__ row_ptr)
{
  __shared__ int s[1024];
  int tid = threadIdx.x;
  int base = tid * STRIP;
  int sum = 0;
  for (int i = 0; i < STRIP; ++i) { int idx = base + i; sum += (idx < NN) ? counts[idx] : 0; }
  s[tid] = sum;
  __syncthreads();
  for (int off = 1; off < 1024; off <<= 1) {
    int v = s[tid];
    int add = (tid >= off) ? s[tid - off] : 0;
    __syncthreads();
    s[tid] = v + add;
    __syncthreads();
  }
  int running = (tid == 0) ? 0 : s[tid - 1];
  for (int i = 0; i < STRIP; ++i) {
    int idx = base + i;
    if (idx < NN) { row_ptr[idx] = running; running += counts[idx]; }
  }
  if (tid == 1023) row_ptr[NN] = running;
}

// ---------------- fused MFMA conv (single pass, swapped operands) + alpha.
// alpha is stored as exp(q.k): softmax is shift-invariant and |q.k| is O(10)
// for this model, so no max subtraction is needed; out_kernel's inner loop
// becomes pure FMA. v/alpha scatter-written at row_ptr[dst] + edge_rel[e].
__global__ __launch_bounds__(256, 2) void conv_fused_kernel(
    const float* __restrict__ node_attr, const float* __restrict__ edge_attr,
    const float* __restrict__ edge_sh, const int* __restrict__ edge_index,
    const float* __restrict__ b1v, const float* __restrict__ b1k,
    const u16* __restrict__ wt, const u16* __restrict__ qw,
    const int* __restrict__ row_ptr, const int* __restrict__ edge_rel,
    u16* __restrict__ v_out, float* __restrict__ alpha)
{
  __shared__ __align__(16) u16 sC[64 * 40];    // fused [EA(16)|SH(16)|pad(8)]
  __shared__ __align__(16) u16 sX[64 * 136];   // t_v -> v result
  __shared__ __align__(16) u16 sTk[64 * 136];  // t_k
  __shared__ __align__(16) u16 sHv[64 * 72];   // relu(EA@W1v+b)
  __shared__ __align__(16) u16 sHk[64 * 72];   // relu(EA@W1k+b) -> k result
  uint4* sC4 = (uint4*)sC; u32* sC32 = (u32*)sC;
  uint4* sX4 = (uint4*)sX;
  uint4* sTk4 = (uint4*)sTk;
  uint4* sHv4 = (uint4*)sHv;
  uint4* sHk4 = (uint4*)sHk;
  const uint4* wt4 = (const uint4*)wt;

  const int tid = threadIdx.x;
  const int wv = tid >> 6, lane = tid & 63, lq = lane >> 4, ln = lane & 15;
  const int e0 = blockIdx.x * 64;
  const int nA = wv * 16 + ln, nB = (wv + 4) * 16 + ln;
  const int cb  = wv * 16 + 4 * lq;   // H-channel base (natural rows)
  const int cb8 = wv * 32 + 8 * lq;   // T-channel base (chperm rows)

  // dst q gather + CSR position (arithmetic from row_ptr + rel) early
  const int el = tid >> 2, p = tid & 3;
  int dq = edge_index[NE + e0 + el]; if ((u32)dq >= NN) dq = 0;
  const uint4* qptr = (const uint4*)(qw + (size_t)dq * 64 + p * 16);
  uint4 q0 = qptr[0], q1 = qptr[1];
  int pos_el = row_ptr[dq] + edge_rel[e0 + el];
  if ((u32)pos_el >= NE) pos_el = 0;

  // src indices for the 4 edges this thread computes in phase A
  int srcs[4];
#pragma unroll
  for (int et = 0; et < 4; ++et) {
    int s = edge_index[e0 + et * 16 + ln];
    if ((u32)s >= NN) s = 0;
    srcs[et] = s;
  }

  // phase-A weight fragments
  uint4 rW1V    = wt4[640 + nA * 5 + lq];
  uint4 rW1K    = wt4[4928 + nA * 5 + lq];
  uint4 rWangV0 = wt4[nA * 5 + lq],        rWangV1 = wt4[nB * 5 + lq];
  uint4 rWangK0 = wt4[4288 + nA * 5 + lq], rWangK1 = wt4[4288 + nB * 5 + lq];
  float4 bV = *(const float4*)(b1v + cb);
  float4 bK = *(const float4*)(b1k + cb);

  // stage fused EA|SH operand
  {
    int r = tid >> 2, kq = tid & 3;
    float4 ea = ((const float4*)(edge_attr + (size_t)(e0 + r) * 16))[kq];
    *(uint2*)(sC32 + r * 20 + kq * 2) = make_uint2(packb(ea.x, ea.y), packb(ea.z, ea.w));
    float4 sh = ((const float4*)(edge_sh + (size_t)(e0 + r) * 16))[kq];
    *(uint2*)(sC32 + r * 20 + 8 + kq * 2) = make_uint2(packb(sh.x, sh.y), packb(sh.z, sh.w));
  }
  // x prefetch for et=0 (channels cb8..cb8+7, f32, straight to regs)
  const float* xp0 = node_attr + (size_t)srcs[0] * 128 + cb8;
  float4 xa = *(const float4*)xp0;
  float4 xb = *(const float4*)(xp0 + 4);
  __syncthreads();   // S1

  const f32x4 z4 = {0.f, 0.f, 0.f, 0.f};
  // ---- phase A: radial MLP hidden + depthwise SH products
#pragma unroll
  for (int et = 0; et < 4; ++et) {
    float4 xa_n, xb_n;
    if (et < 3) {
      const float* xp = node_attr + (size_t)srcs[et + 1] * 128 + cb8;
      xa_n = *(const float4*)xp;
      xb_n = *(const float4*)(xp + 4);
    }
    uint4 aC = sC4[(et * 16 + ln) * 5 + lq];
    f32x4 hv  = mf32(rW1V, aC, z4);
    f32x4 hk  = mf32(rW1K, aC, z4);
    f32x4 t0v = mf32(rWangV0, aC, z4);
    f32x4 t1v = mf32(rWangV1, aC, z4);
    f32x4 t0k = mf32(rWangK0, aC, z4);
    f32x4 t1k = mf32(rWangK1, aC, z4);
    const int edge = et * 16 + ln;
    sX4[edge * 17 + 4 * wv + lq] = make_uint4(
        packb(t0v[0] * xa.x, t0v[1] * xa.y), packb(t0v[2] * xa.z, t0v[3] * xa.w),
        packb(t1v[0] * xb.x, t1v[1] * xb.y), packb(t1v[2] * xb.z, t1v[3] * xb.w));
    sTk4[edge * 17 + 4 * wv + lq] = make_uint4(
        packb(t0k[0] * xa.x, t0k[1] * xa.y), packb(t0k[2] * xa.z, t0k[3] * xa.w),
        packb(t1k[0] * xb.x, t1k[1] * xb.y), packb(t1k[2] * xb.z, t1k[3] * xb.w));
    *(uint2*)(sHv + edge * 72 + cb) = make_uint2(
        packb(fmaxf(hv[0] + bV.x, 0.f), fmaxf(hv[1] + bV.y, 0.f)),
        packb(fmaxf(hv[2] + bV.z, 0.f), fmaxf(hv[3] + bV.w, 0.f)));
    *(uint2*)(sHk + edge * 72 + cb) = make_uint2(
        packb(fmaxf(hk[0] + bK.x, 0.f), fmaxf(hk[1] + bK.y, 0.f)),
        packb(fmaxf(hk[2] + bK.z, 0.f), fmaxf(hk[3] + bK.w, 0.f)));
    xa = xa_n; xb = xb_n;
  }

  // phase-B weight fragments (issued here; in flight across the barrier)
  uint4 rWlinV[2][4], rWlinK[4], rW2V[2][2], rW2K[2];
#pragma unroll
  for (int ks = 0; ks < 4; ++ks) {
    rWlinV[0][ks] = wt4[960 + nA * 17 + ks * 4 + lq];
    rWlinV[1][ks] = wt4[960 + nB * 17 + ks * 4 + lq];
    rWlinK[ks]    = wt4[5248 + nA * 17 + ks * 4 + lq];
  }
#pragma unroll
  for (int ks = 0; ks < 2; ++ks) {
    rW2V[0][ks] = wt4[3136 + nA * 9 + ks * 4 + lq];
    rW2V[1][ks] = wt4[3136 + nB * 9 + ks * 4 + lq];
    rW2K[ks]    = wt4[6336 + nA * 9 + ks * 4 + lq];
  }
  __syncthreads();  // S2

  // ---- phase B: channel-mix (Wlin) and radial out (W2); results packed in regs
  uint4 pv[4]; uint2 pk[4];
#pragma unroll
  for (int et = 0; et < 4; ++et) {
    const int er = et * 16 + ln;
    f32x4 acc0 = z4, acc1 = z4, acck = z4;
#pragma unroll
    for (int ks = 0; ks < 4; ++ks) {
      uint4 tb = sX4[er * 17 + ks * 4 + lq];
      acc0 = mf32(rWlinV[0][ks], tb, acc0);
      acc1 = mf32(rWlinV[1][ks], tb, acc1);
      acck = mf32(rWlinK[ks], sTk4[er * 17 + ks * 4 + lq], acck);
    }
    f32x4 b0 = z4, b1 = z4, bk = z4;
#pragma unroll
    for (int ks = 0; ks < 2; ++ks) {
      uint4 hb = sHv4[er * 9 + ks * 4 + lq];
      b0 = mf32(rW2V[0][ks], hb, b0);
      b1 = mf32(rW2V[1][ks], hb, b1);
      bk = mf32(rW2K[ks], sHk4[er * 9 + ks * 4 + lq], bk);
    }
    pv[et] = make_uint4(packb(acc0[0] * b0[0], acc0[1] * b0[1]),
                        packb(acc0[2] * b0[2], acc0[3] * b0[3]),
                        packb(acc1[0] * b1[0], acc1[1] * b1[1]),
                        packb(acc1[2] * b1[2], acc1[3] * b1[3]));
    pk[et] = make_uint2(packb(acck[0] * bk[0], acck[1] * bk[1]),
                        packb(acck[2] * bk[2], acck[3] * bk[3]));
  }
  __syncthreads();  // S3

  // ---- result staging: v as b128 (channels cb8..cb8+7), k as b64
#pragma unroll
  for (int et = 0; et < 4; ++et) {
    const int edge = et * 16 + ln;
    sX4[edge * 17 + 4 * wv + lq] = pv[et];
    *(uint2*)(sHk + edge * 72 + cb) = pk[et];
  }
  __syncthreads();  // S4

  // v store, scattered to CSR slot (256B contiguous per edge; row==el)
  {
    int row = tid >> 2, seg = tid & 3;
    uint4* gp = (uint4*)(v_out + (size_t)pos_el * 128);
#pragma unroll
    for (int i = 0; i < 4; ++i) gp[seg * 4 + i] = sX4[row * 17 + seg * 4 + i];
  }
  // alpha = exp(q . k)  (bf16 dot2 + expf), scattered to CSR slot
  {
    uint4 k0 = sHk4[el * 9 + p * 2];
    uint4 k1 = sHk4[el * 9 + p * 2 + 1];
    float a0 = 0.f, a1 = 0.f;
    a0 = dot2b(q0.x, k0.x, a0); a0 = dot2b(q0.y, k0.y, a0);
    a0 = dot2b(q0.z, k0.z, a0); a0 = dot2b(q0.w, k0.w, a0);
    a1 = dot2b(q1.x, k1.x, a1); a1 = dot2b(q1.y, k1.y, a1);
    a1 = dot2b(q1.z, k1.z, a1); a1 = dot2b(q1.w, k1.w, a1);
    ((float2*)(alpha + (size_t)pos_el * 8))[p] = make_float2(__expf(a0), __expf(a1));
  }
}

// ---------------- per-node weighted sum over SEQUENTIAL CSR-ordered
// exp(alpha)/v streams. Wave processes 2 EDGES per iteration (sub=lane>>5),
// each lane covering 4 channels via uint2 (8B) loads -> half the loop trips
// and half the load instructions of the u32 variant. Sub-wave partials merged
// with one shfl_xor(32) pair per node. MFMA @Wout epilogue unchanged.
__global__ __launch_bounds__(256) void out_kernel(
    const int* __restrict__ row_ptr,
    const float* __restrict__ alpha, const u16* __restrict__ v_e,
    const u16* __restrict__ wt, float* __restrict__ out)
{
  __shared__ __align__(16) u16 sAgg[16 * 136];
  u32* sAgg32 = (u32*)sAgg;
  uint4* sAgg4 = (uint4*)sAgg;
  const uint4* wt4 = (const uint4*)wt;
  const int tid = threadIdx.x, wv = tid >> 6, lane = tid & 63, lq = lane >> 4, ln = lane & 15;
  const f32x4 z4 = {0.f, 0.f, 0.f, 0.f};
  uint4 rWT[2][4];
#pragma unroll
  for (int c = 0; c < 2; ++c) {
    int n = (wv * 2 + c) * 16 + ln;
#pragma unroll
    for (int ks = 0; ks < 4; ++ks) rWT[c][ks] = wt4[6912 + n * 17 + ks * 4 + lq];
  }
  const int sub = lane >> 5;     // which of 2 concurrent edges
  const int l5  = lane & 31;     // channel group: channels l5*4 .. l5*4+3
  const int hh5 = l5 >> 2;       // head of those 4 channels
  const int grp = blockIdx.x;
#pragma unroll 1
  for (int i = 0; i < 4; ++i) {
    int n = grp * 16 + wv * 4 + i;
    int beg = row_ptr[n], end = row_ptr[n + 1];
    if (beg < 0) beg = 0; if (beg > NE) beg = NE;
    if (end < beg) end = beg; if (end > NE) end = NE;
    int deg = end - beg;
    float A0 = 0.f, A1 = 0.f, A2 = 0.f, A3 = 0.f, l = 0.f;
    int j = 0;
#pragma unroll 1
    for (; j + 4 <= deg; j += 4) {
      size_t ea = (size_t)(beg + j + sub);
      size_t eb = ea + 2;
      float w0 = alpha[ea * 8 + hh5];
      uint2  x0 = *(const uint2*)(v_e + ea * 128 + l5 * 4);
      float w1 = alpha[eb * 8 + hh5];
      uint2  x1 = *(const uint2*)(v_e + eb * 128 + l5 * 4);
      l += w0;
      A0 = fmaf(w0, b2f_lo(x0.x), A0); A1 = fmaf(w0, b2f_hi(x0.x), A1);
      A2 = fmaf(w0, b2f_lo(x0.y), A2); A3 = fmaf(w0, b2f_hi(x0.y), A3);
      l += w1;
      A0 = fmaf(w1, b2f_lo(x1.x), A0); A1 = fmaf(w1, b2f_hi(x1.x), A1);
      A2 = fmaf(w1, b2f_lo(x1.y), A2); A3 = fmaf(w1, b2f_hi(x1.y), A3);
    }
#pragma unroll 1
    for (; j < deg; j += 2) {
      int jj = j + sub;
      bool valid = jj < deg;
      size_t e = (size_t)(beg + (valid ? jj : 0));
      float w = valid ? alpha[e * 8 + hh5] : 0.f;
      uint2 x = *(const uint2*)(v_e + e * 128 + l5 * 4);
      l += w;
      A0 = fmaf(w, b2f_lo(x.x), A0); A1 = fmaf(w, b2f_hi(x.x), A1);
      A2 = fmaf(w, b2f_lo(x.y), A2); A3 = fmaf(w, b2f_hi(x.y), A3);
    }
    // merge the two sub-wave partials (lane <-> lane^32)
    A0 += __shfl_xor(A0, 32); A1 += __shfl_xor(A1, 32);
    A2 += __shfl_xor(A2, 32); A3 += __shfl_xor(A3, 32);
    l  += __shfl_xor(l, 32);
    float inv = (l > 0.f) ? (1.f / l) : 0.f;
    if (sub == 0) {
      sAgg32[(wv * 4 + i) * 68 + l5 * 2]     = packb(A0 * inv, A1 * inv);
      sAgg32[(wv * 4 + i) * 68 + l5 * 2 + 1] = packb(A2 * inv, A3 * inv);
    }
  }
  __syncthreads();
#pragma unroll
  for (int c = 0; c < 2; ++c) {
    f32x4 acc = z4;
#pragma unroll
    for (int ks = 0; ks < 4; ++ks) acc = mf32(sAgg4[ln * 17 + ks * 4 + lq], rWT[c][ks], acc);
    int col = (wv * 2 + c) * 16 + ln;
#pragma unroll
    for (int r = 0; r < 4; ++r)
      out[(size_t)(grp * 16 + lq * 4 + r) * 128 + col] = acc[r];
  }
}

extern "C" void kernel_launch(void* const* d_in, const int* in_sizes, int n_in,
                              void* d_out, int out_size, void* d_ws, size_t ws_size,
                              hipStream_t stream)
{
  const float* node_attr = (const float*)d_in[0];
  const float* edge_attr = (const float*)d_in[1];
  const float* edge_sh   = (const float*)d_in[2];
  const float* Wq        = (const float*)d_in[3];
  const float* Wang_k    = (const float*)d_in[4];
  const float* Wlin_k    = (const float*)d_in[5];
  const float* W1k       = (const float*)d_in[6];
  const float* b1k       = (const float*)d_in[7];
  const float* W2k       = (const float*)d_in[8];
  const float* Wang_v    = (const float*)d_in[9];
  const float* Wlin_v    = (const float*)d_in[10];
  const float* W1v       = (const float*)d_in[11];
  const float* b1v       = (const float*)d_in[12];
  const float* W2v       = (const float*)d_in[13];
  const float* Wdot      = (const float*)d_in[14];
  const float* Wout      = (const float*)d_in[15];
  const int* edge_index  = (const int*)d_in[16];
  float* out = (float*)d_out;

  char* ws = (char*)d_ws;
  u16*   v_e      = (u16*)(ws + 0);                 // E*128*2  = 204,800,000 (CSR order)
  float* alpha    = (float*)(ws + 204800000);       // E*8*4    =  25,600,000 (CSR order, exp'd)
  u16*   qw       = (u16*)(ws + 230400000);         // N*64*2   =   6,400,000
  int*   counts   = (int*)(ws + 236800000);         // 200,064
  int*   row_ptr  = (int*)(ws + 237000064);         // 200,064
  int*   edge_rel = (int*)(ws + 237400192);         // 3,200,000 (within-segment rank)
  u16*   wt       = (u16*)(ws + 240600192);         // 162,816 -> total 240,763,008

  zero_kernel<<<dim3((NN + 255) / 256), dim3(256), 0, stream>>>(counts);
  prep_w_kernel<<<dim3((WT_TOTAL + 255) / 256), dim3(256), 0, stream>>>(
      Wang_v, W1v, Wlin_v, W2v, Wang_k, W1k, Wlin_k, W2k, Wout, Wq, Wdot, wt);
  qw_kernel<<<dim3((NN + 63) / 64), dim3(256), 0, stream>>>(node_attr, wt, qw);
  count_kernel<<<dim3((NE + 255) / 256), dim3(256), 0, stream>>>(edge_index, counts, edge_rel);
  scan_kernel<<<dim3(1), dim3(1024), 0, stream>>>(counts, row_ptr);
  conv_fused_kernel<<<dim3(NE / 64), dim3(256), 0, stream>>>(
      node_attr, edge_attr, edge_sh, edge_index, b1v, b1k, wt, qw, row_ptr, edge_rel, v_e, alpha);
  out_kernel<<<dim3(3125), dim3(256), 0, stream>>>(row_ptr, alpha, v_e, wt, out);
}